// Round 3
// baseline (262.088 us; speedup 1.0000x reference)
//
#include <hip/hip_runtime.h>
#include <math.h>

#define NB 4
#define HID 4096
#define CKV 512
#define CQ 1536
#define NH 32
#define HD 128
#define RD 64
#define SS 4096
#define SK 4097
#define SKP 4100  // padded scores row stride (16B-aligned float4 rows)

#define SCALE_F 0.07216878364870322f  // 1/sqrt(192)

// workspace offsets (floats) — [WS_CKV, WS_ZERO_N) memset to 0 each call
enum : int {
  WS_CKV    = 0,                       // [NB][CKV]      (zeroed, atomic)
  WS_CQ     = WS_CKV + NB*CKV,         // [NB][CQ]       (zeroed, atomic)
  WS_KRRAW  = WS_CQ + NB*CQ,           // [NB][RD]       (zeroed, atomic)
  WS_QC     = WS_KRRAW + NB*RD,        // [NB][HID]      (zeroed, atomic)
  WS_QRRAW  = WS_QC + NB*HID,          // [NB][NH*RD]    (zeroed, atomic)
  WS_OLAT   = WS_QRRAW + NB*NH*RD,     // [NB][NH][CKV]  (zeroed, atomic)
  WS_ATTN   = WS_OLAT + NB*NH*CKV,     // [NB][HID]      (zeroed, atomic)
  WS_ZERO_N = WS_ATTN + NB*HID,        // = 114944
  WS_QABS   = WS_ZERO_N,               // [NB][NH][CKV]  (pre-scaled by SCALE_F)
  WS_QROPE  = WS_QABS + NB*NH*CKV,     // [NB][NH][RD]   (pre-scaled by SCALE_F)
  WS_KROPE  = WS_QROPE + NB*NH*RD,     // [NB][RD]       (unscaled)
  WS_SCORES = WS_KROPE + NB*RD,        // [NB][NH][SKP]
  WS_TOTAL  = WS_SCORES + NB*NH*SKP
};

__device__ inline void fma4(float4& a, float s, const float4& v) {
  a.x += s*v.x; a.y += s*v.y; a.z += s*v.z; a.w += s*v.w;
}
__device__ inline float dot4(const float4& a, const float4& b) {
  return a.x*b.x + a.y*b.y + a.z*b.z + a.w*b.w;
}

// ---------------- K1: hidden -> c_KV, c_Q, k_R_raw ---------------------------
// thread = 4 cols (float4), k-chunk 32, no LDS; grid (3, 128) = 384 blocks.
__global__ __launch_bounds__(256)
void k_proj1(const float* __restrict__ hidden,
             const float* __restrict__ Wdkv,
             const float* __restrict__ Wdq,
             const float* __restrict__ Wkr,
             float* __restrict__ ws) {
  const int col4 = blockIdx.x * 256 + threadIdx.x;
  const int k0 = blockIdx.y * 32;
  const float* W; int C4; int wcol4; float* dst;
  if (col4 < 128)      { W = Wdkv; C4 = 128; wcol4 = col4;       dst = ws + WS_CKV; }
  else if (col4 < 512) { W = Wdq;  C4 = 384; wcol4 = col4 - 128; dst = ws + WS_CQ; }
  else if (col4 < 528) { W = Wkr;  C4 = 16;  wcol4 = col4 - 512; dst = ws + WS_KRRAW; }
  else return;
  const float4* wp = (const float4*)W + (size_t)k0 * C4 + wcol4;
  float4 acc[NB] = {};
  #pragma unroll 4
  for (int i = 0; i < 32; ++i) {
    float4 w4 = wp[(size_t)i * C4];
    #pragma unroll
    for (int b = 0; b < NB; ++b) fma4(acc[b], hidden[b*HID + k0 + i], w4);
  }
  #pragma unroll
  for (int b = 0; b < NB; ++b) {
    float* d = dst + b*C4*4 + wcol4*4;
    atomicAdd(d+0, acc[b].x); atomicAdd(d+1, acc[b].y);
    atomicAdd(d+2, acc[b].z); atomicAdd(d+3, acc[b].w);
  }
}

// ---------------- K2: c_Q -> q_C, q_R_raw ------------------------------------
// grid (6, 48) = 288 blocks; k-chunk 32 over CQ=1536.
__global__ __launch_bounds__(256)
void k_proj2(const float* __restrict__ Wuq,
             const float* __restrict__ Wqr,
             float* __restrict__ ws) {
  const int col4 = blockIdx.x * 256 + threadIdx.x;  // < 1536
  const int k0 = blockIdx.y * 32;
  const float* W; int C4; int wcol4; float* dst;
  if (col4 < 1024) { W = Wuq; C4 = 1024; wcol4 = col4;        dst = ws + WS_QC; }
  else             { W = Wqr; C4 = 512;  wcol4 = col4 - 1024; dst = ws + WS_QRRAW; }
  const float4* wp = (const float4*)W + (size_t)k0 * C4 + wcol4;
  const float* act = ws + WS_CQ;
  float4 acc[NB] = {};
  #pragma unroll 4
  for (int i = 0; i < 32; ++i) {
    float4 w4 = wp[(size_t)i * C4];
    #pragma unroll
    for (int b = 0; b < NB; ++b) fma4(acc[b], act[b*CQ + k0 + i], w4);
  }
  #pragma unroll
  for (int b = 0; b < NB; ++b) {
    float* d = dst + b*C4*4 + wcol4*4;
    atomicAdd(d+0, acc[b].x); atomicAdd(d+1, acc[b].y);
    atomicAdd(d+2, acc[b].z); atomicAdd(d+3, acc[b].w);
  }
}

// -------- K3: q_abs = q_C @ W_UK^T per head (×SCALE); RoPE; new cache rows ---
// 257 blocks: 256 compute (h × 8 c-slices of 64) + 1 rope block.
__global__ __launch_bounds__(256)
void k_absorb_rope(const float* __restrict__ Wuk,
                   float* __restrict__ ws,
                   float* __restrict__ out_ckv,
                   float* __restrict__ out_kr) {
  const int bid = blockIdx.x, tid = threadIdx.x;
  if (bid < 256) {
    const int h = bid >> 3, cq = bid & 7;
    __shared__ float qc_s[NB][HD];
    __shared__ float part_s[NB][256];
    for (int e = tid; e < NB*HD; e += 256) {
      int b = e >> 7, d = e & 127;
      qc_s[b][d] = ws[WS_QC + b*HID + h*HD + d];
    }
    __syncthreads();
    const int c = cq*64 + (tid & 63);
    const int dg = tid >> 6;           // 0..3, 32 d each
    const float4* wrow = (const float4*)(Wuk + (size_t)c*(NH*HD) + h*HD + dg*32);
    float acc[NB] = {0,0,0,0};
    #pragma unroll
    for (int d4 = 0; d4 < 8; ++d4) {
      float4 w4 = wrow[d4];
      #pragma unroll
      for (int b = 0; b < NB; ++b)
        acc[b] += dot4(w4, *(const float4*)&qc_s[b][dg*32 + d4*4]);
    }
    #pragma unroll
    for (int b = 0; b < NB; ++b) part_s[b][tid] = acc[b];
    __syncthreads();
    if (tid < 64) {
      #pragma unroll
      for (int b = 0; b < NB; ++b) {
        float v = part_s[b][tid] + part_s[b][tid+64] + part_s[b][tid+128] + part_s[b][tid+192];
        ws[WS_QABS + (size_t)(b*NH + h)*CKV + cq*64 + tid] = v * SCALE_F;
      }
    }
  } else {
    const double LN1E4 = 9.210340371976184;  // ln(10000)
    for (int pid = tid; pid < NB*NH*32; pid += 256) {
      int b = pid >> 10, rem = pid & 1023, h = rem >> 5, i = rem & 31;
      double ang = 4096.0 * exp(-(double)i / 32.0 * LN1E4);
      float cs = (float)cos(ang), sn = (float)sin(ang);
      float x1 = ws[WS_QRRAW + b*(NH*RD) + h*RD + 2*i];
      float x2 = ws[WS_QRRAW + b*(NH*RD) + h*RD + 2*i + 1];
      ws[WS_QROPE + (b*NH + h)*RD + 2*i]     = (x1*cs - x2*sn) * SCALE_F;
      ws[WS_QROPE + (b*NH + h)*RD + 2*i + 1] = (x1*sn + x2*cs) * SCALE_F;
    }
    if (tid < NB*32) {
      int b = tid >> 5, i = tid & 31;
      double ang = 4096.0 * exp(-(double)i / 32.0 * LN1E4);
      float cs = (float)cos(ang), sn = (float)sin(ang);
      float x1 = ws[WS_KRRAW + b*RD + 2*i];
      float x2 = ws[WS_KRRAW + b*RD + 2*i + 1];
      float o0 = x1*cs - x2*sn, o1 = x1*sn + x2*cs;
      ws[WS_KROPE + b*RD + 2*i]     = o0;
      ws[WS_KROPE + b*RD + 2*i + 1] = o1;
      out_kr[(size_t)b*SK*RD + (size_t)SS*RD + 2*i]     = o0;
      out_kr[(size_t)b*SK*RD + (size_t)SS*RD + 2*i + 1] = o1;
    }
    for (int e = tid; e < NB*CKV; e += 256) {
      int b = e >> 9, cc = e & 511;
      out_ckv[(size_t)b*SK*CKV + (size_t)SS*CKV + cc] = ws[WS_CKV + b*CKV + cc];
    }
  }
}

// ---------------- K4: scores — wave-autonomous, no LDS, no atomics ----------
// wave: 16 keys × 8 heads; lane = (kq 0..3, cg 0..15); full K=576 in regs,
// shfl_xor reduce over the 16 c-groups. grid (65, 4, 4) = 1040 blocks.
__global__ __launch_bounds__(256)
void k_scores(const float* __restrict__ kv_cache,
              const float* __restrict__ kr_cache,
              float* __restrict__ ws) {
  const int tid = threadIdx.x;
  const int wid = tid >> 6, lane = tid & 63;
  const int kq = lane >> 4, cg = lane & 15;
  const int b = blockIdx.z;
  const int h0 = blockIdx.y * 8;
  const int kw0 = blockIdx.x * 64 + wid * 16;

  const float* ckv_base[4];
  const float* kr_base[4];
  #pragma unroll
  for (int t = 0; t < 4; ++t) {
    int k = kw0 + t*4 + kq;
    if (k < SS)       { ckv_base[t] = kv_cache + ((size_t)b*SS + k)*CKV + cg*4;
                        kr_base[t]  = kr_cache + ((size_t)b*SS + k)*RD + cg*4; }
    else if (k == SS) { ckv_base[t] = ws + WS_CKV + b*CKV + cg*4;
                        kr_base[t]  = ws + WS_KROPE + b*RD + cg*4; }
    else              { ckv_base[t] = ws + WS_CKV + cg*4;      // dummy, store guarded
                        kr_base[t]  = ws + WS_KROPE + cg*4; }
  }
  const size_t qbase  = WS_QABS  + (size_t)(b*NH + h0)*CKV + cg*4;
  const size_t qrbase = WS_QROPE + (size_t)(b*NH + h0)*RD  + cg*4;

  float acc[8][4] = {};
  #pragma unroll 2
  for (int p = 0; p < 8; ++p) {
    float4 kv4[4], q4[8];
    #pragma unroll
    for (int t = 0; t < 4; ++t) kv4[t] = *(const float4*)(ckv_base[t] + p*64);
    #pragma unroll
    for (int h = 0; h < 8; ++h) q4[h] = *(const float4*)(ws + qbase + h*CKV + p*64);
    #pragma unroll
    for (int h = 0; h < 8; ++h)
      #pragma unroll
      for (int t = 0; t < 4; ++t)
        acc[h][t] += dot4(q4[h], kv4[t]);
  }
  {  // rope tail
    float4 kv4[4], q4[8];
    #pragma unroll
    for (int t = 0; t < 4; ++t) kv4[t] = *(const float4*)(kr_base[t]);
    #pragma unroll
    for (int h = 0; h < 8; ++h) q4[h] = *(const float4*)(ws + qrbase + h*RD);
    #pragma unroll
    for (int h = 0; h < 8; ++h)
      #pragma unroll
      for (int t = 0; t < 4; ++t)
        acc[h][t] += dot4(q4[h], kv4[t]);
  }
  #pragma unroll
  for (int h = 0; h < 8; ++h) {
    #pragma unroll
    for (int t = 0; t < 4; ++t) {
      float v = acc[h][t];
      v += __shfl_xor(v, 1);
      v += __shfl_xor(v, 2);
      v += __shfl_xor(v, 4);
      v += __shfl_xor(v, 8);
      if (cg == h) {
        int k = kw0 + t*4 + kq;
        if (k < SK)
          ws[WS_SCORES + (size_t)(b*NH + h0 + h)*SKP + k] = v;
      }
    }
  }
}

// ---------------- K5: row softmax over SK (applies mask) --------------------
__global__ __launch_bounds__(256)
void k_softmax(const float* __restrict__ mask, float* __restrict__ ws) {
  __shared__ float red[256];
  const int tid = threadIdx.x;
  const int b = blockIdx.x >> 5;
  float* s = ws + WS_SCORES + (size_t)blockIdx.x * SKP;
  const float* mrow = mask + (size_t)b * SK;
  float v[17];
  float m = -INFINITY;
  #pragma unroll
  for (int r = 0; r < 17; ++r) {
    int k = tid + r*256;
    v[r] = (k < SK) ? (s[k] + mrow[k] * (-1e9f)) : -INFINITY;
    m = fmaxf(m, v[r]);
  }
  red[tid] = m; __syncthreads();
  for (int st = 128; st > 0; st >>= 1) {
    if (tid < st) red[tid] = fmaxf(red[tid], red[tid+st]);
    __syncthreads();
  }
  m = red[0]; __syncthreads();
  float e[17];
  float l = 0.f;
  #pragma unroll
  for (int r = 0; r < 17; ++r) {
    int k = tid + r*256;
    e[r] = (k < SK) ? __expf(v[r] - m) : 0.f;
    l += e[r];
  }
  red[tid] = l; __syncthreads();
  for (int st = 128; st > 0; st >>= 1) {
    if (tid < st) red[tid] += red[tid+st];
    __syncthreads();
  }
  float inv = 1.f / red[0];
  #pragma unroll
  for (int r = 0; r < 17; ++r) {
    int k = tid + r*256;
    if (k < SK) s[k] = e[r] * inv;
  }
}

// ---------------- K6: o_latent = probs @ c_KV — wave-autonomous -------------
// wave: 8 heads × 256 c (lane = float4 c-slot); 64-key chunk; atomics.
// grid (65, 2, 4) = 520 blocks.
__global__ __launch_bounds__(256)
void k_pv(const float* __restrict__ kv_cache, float* __restrict__ ws) {
  const int tid = threadIdx.x, wid = tid >> 6, lane = tid & 63;
  const int b = blockIdx.z;
  const int h0 = blockIdx.y * 16 + (wid >> 1) * 8;
  const int c  = (wid & 1) * 256 + lane * 4;
  const int k0 = blockIdx.x * 64;
  const size_t srow0 = WS_SCORES + (size_t)(b*NH + h0) * SKP;
  float4 acc[8] = {};
  if (k0 < SS) {
    const float* kvp = kv_cache + ((size_t)b*SS + k0)*CKV + c;
    #pragma unroll 2
    for (int kk = 0; kk < 64; kk += 4) {
      float4 p4[8], kv4[4];
      #pragma unroll
      for (int h = 0; h < 8; ++h)
        p4[h] = *(const float4*)(ws + srow0 + (size_t)h*SKP + k0 + kk);
      #pragma unroll
      for (int j = 0; j < 4; ++j)
        kv4[j] = *(const float4*)(kvp + (size_t)(kk + j)*CKV);
      #pragma unroll
      for (int h = 0; h < 8; ++h) {
        fma4(acc[h], p4[h].x, kv4[0]);
        fma4(acc[h], p4[h].y, kv4[1]);
        fma4(acc[h], p4[h].z, kv4[2]);
        fma4(acc[h], p4[h].w, kv4[3]);
      }
    }
  } else {  // final chunk: only k == SS
    float4 kv = *(const float4*)(ws + WS_CKV + b*CKV + c);
    #pragma unroll
    for (int h = 0; h < 8; ++h)
      fma4(acc[h], ws[srow0 + (size_t)h*SKP + SS], kv);
  }
  #pragma unroll
  for (int h = 0; h < 8; ++h) {
    float* dst = ws + WS_OLAT + (size_t)(b*NH + h0 + h)*CKV + c;
    atomicAdd(dst+0, acc[h].x); atomicAdd(dst+1, acc[h].y);
    atomicAdd(dst+2, acc[h].z); atomicAdd(dst+3, acc[h].w);
  }
}

// ---------------- K7: attn = o_latent @ W_UV (per head, block-diagonal) -----
// thread = float4 cols; col4 -> head = col4>>5; k-chunk 16; grid (4, 32).
__global__ __launch_bounds__(256)
void k_uv(const float* __restrict__ Wuv, float* __restrict__ ws) {
  const int col4 = blockIdx.x * 256 + threadIdx.x;  // < 1024
  const int h = col4 >> 5;
  const int k0 = blockIdx.y * 16;                   // within CKV
  const float4* wp = (const float4*)Wuv + (size_t)k0 * 1024 + col4;
  float4 acc[NB] = {};
  #pragma unroll 4
  for (int i = 0; i < 16; ++i) {
    float4 w4 = wp[(size_t)i * 1024];
    #pragma unroll
    for (int b = 0; b < NB; ++b)
      fma4(acc[b], ws[WS_OLAT + (size_t)(b*NH + h)*CKV + k0 + i], w4);
  }
  #pragma unroll
  for (int b = 0; b < NB; ++b) {
    float* d = ws + WS_ATTN + b*HID + col4*4;
    atomicAdd(d+0, acc[b].x); atomicAdd(d+1, acc[b].y);
    atomicAdd(d+2, acc[b].z); atomicAdd(d+3, acc[b].w);
  }
}

// ---------------- K8: out = attn @ W_O ---------------------------------------
// thread = float4 cols; k-chunk 32; grid (4, 128) = 512 blocks.
__global__ __launch_bounds__(256)
void k_wo(const float* __restrict__ Wo, const float* __restrict__ ws,
          float* __restrict__ out) {
  const int col4 = blockIdx.x * 256 + threadIdx.x;  // < 1024
  const int k0 = blockIdx.y * 32;
  const float4* wp = (const float4*)Wo + (size_t)k0 * 1024 + col4;
  float4 acc[NB] = {};
  #pragma unroll 4
  for (int i = 0; i < 32; ++i) {
    float4 w4 = wp[(size_t)i * 1024];
    #pragma unroll
    for (int b = 0; b < NB; ++b)
      fma4(acc[b], ws[WS_ATTN + b*HID + k0 + i], w4);
  }
  #pragma unroll
  for (int b = 0; b < NB; ++b) {
    float* d = out + b*HID + col4*4;
    atomicAdd(d+0, acc[b].x); atomicAdd(d+1, acc[b].y);
    atomicAdd(d+2, acc[b].z); atomicAdd(d+3, acc[b].w);
  }
}

// ---------------- K9: cache copy (rows 0..4095), no div ----------------------
__global__ __launch_bounds__(256)
void k_copy(const float4* __restrict__ src_ckv,
            const float4* __restrict__ src_kr,
            float4* __restrict__ dst_ckv,
            float4* __restrict__ dst_kr) {
  const int bx = blockIdx.x;
  if (bx < 8192) {
    int b = bx >> 11;
    int idx = (bx & 2047) * 256 + threadIdx.x;      // < SS*CKV/4
    dst_ckv[(size_t)b*(SK*CKV/4) + idx] = src_ckv[(size_t)b*(SS*CKV/4) + idx];
  } else {
    int bx2 = bx - 8192;
    int b = bx2 >> 8;
    int idx = (bx2 & 255) * 256 + threadIdx.x;      // < SS*RD/4
    dst_kr[(size_t)b*(SK*RD/4) + idx] = src_kr[(size_t)b*(SS*RD/4) + idx];
  }
}

extern "C" void kernel_launch(void* const* d_in, const int* in_sizes, int n_in,
                              void* d_out, int out_size, void* d_ws, size_t ws_size,
                              hipStream_t stream) {
  (void)in_sizes; (void)n_in; (void)out_size; (void)ws_size;
  const float* hidden = (const float*)d_in[0];
  const float* mask   = (const float*)d_in[1];
  const float* ckv_c  = (const float*)d_in[2];
  const float* kr_c   = (const float*)d_in[3];
  const float* Wdkv   = (const float*)d_in[4];
  const float* Wuk    = (const float*)d_in[5];
  const float* Wuv    = (const float*)d_in[6];
  const float* Wdq    = (const float*)d_in[7];
  const float* Wuq    = (const float*)d_in[8];
  const float* Wqr    = (const float*)d_in[9];
  const float* Wkr    = (const float*)d_in[10];
  const float* Wo     = (const float*)d_in[11];
  float* out = (float*)d_out;
  float* ws  = (float*)d_ws;
  float* out_ckv = out + NB*HID;
  float* out_kr  = out + NB*HID + (size_t)NB*SK*CKV;

  hipMemsetAsync(ws, 0, (size_t)WS_ZERO_N * sizeof(float), stream);
  hipMemsetAsync(out, 0, (size_t)NB * HID * sizeof(float), stream);

  k_copy<<<9216, 256, 0, stream>>>((const float4*)ckv_c, (const float4*)kr_c,
                                   (float4*)out_ckv, (float4*)out_kr);
  k_proj1<<<dim3(3, 128), 256, 0, stream>>>(hidden, Wdkv, Wdq, Wkr, ws);
  k_proj2<<<dim3(6, 48), 256, 0, stream>>>(Wuq, Wqr, ws);
  k_absorb_rope<<<257, 256, 0, stream>>>(Wuk, ws, out_ckv, out_kr);
  k_scores<<<dim3(65, 4, 4), 256, 0, stream>>>(ckv_c, kr_c, ws);
  k_softmax<<<NB*NH, 256, 0, stream>>>(mask, ws);
  k_pv<<<dim3(65, 2, 4), 256, 0, stream>>>(ckv_c, ws);
  k_uv<<<dim3(4, 32), 256, 0, stream>>>(Wuv, ws);
  k_wo<<<dim3(4, 128), 256, 0, stream>>>(Wo, ws, out);
}

// Round 4
// 218.434 us; speedup vs baseline: 1.1999x; 1.1999x over previous
//
#include <hip/hip_runtime.h>
#include <math.h>

#define NB 4
#define HID 4096
#define CKV 512
#define CQ 1536
#define NH 32
#define HD 128
#define RD 64
#define SS 4096
#define SK 4097
#define SKP 4100  // padded scores row stride (float4-aligned)

#define SCALE_F 0.07216878364870322f  // 1/sqrt(192)

// workspace offsets (floats) — [0, WS_ZERO_N) memset to 0 each call
enum : int {
  WS_CKV    = 0,                       // [NB][CKV]      (zeroed, atomic)
  WS_CQ     = WS_CKV + NB*CKV,         // [NB][CQ]       (zeroed, atomic)
  WS_KRRAW  = WS_CQ + NB*CQ,           // [NB][RD]       (zeroed, atomic)
  WS_QC     = WS_KRRAW + NB*RD,        // [NB][HID]      (zeroed, atomic)
  WS_QRRAW  = WS_QC + NB*HID,          // [NB][NH*RD]    (zeroed, atomic)
  WS_OLAT   = WS_QRRAW + NB*NH*RD,     // [NB][NH][CKV]  (zeroed, atomic)
  WS_ATTN   = WS_OLAT + NB*NH*CKV,     // [NB][HID]      (zeroed, atomic)
  WS_ZERO_N = WS_ATTN + NB*HID,        // = 114944
  WS_QABS   = WS_ZERO_N,               // [NB][NH][CKV]  (pre-scaled)
  WS_QROPE  = WS_QABS + NB*NH*CKV,     // [NB][NH][RD]   (pre-scaled)
  WS_KROPE  = WS_QROPE + NB*NH*RD,     // [NB][RD]
  WS_SCORES = WS_KROPE + NB*RD,        // [NB][NH][SKP]  (zeroed separately, atomic)
  WS_TOTAL  = WS_SCORES + NB*NH*SKP    // 713728 floats = 2.86 MB
};

__device__ inline void fma4(float4& a, float s, const float4& v) {
  a.x += s*v.x; a.y += s*v.y; a.z += s*v.z; a.w += s*v.w;
}
__device__ inline float dot4(const float4& a, const float4& b) {
  return a.x*b.x + a.y*b.y + a.z*b.z + a.w*b.w;
}

// ---------------- K1: hidden -> c_KV, c_Q, k_R_raw ---------------------------
// thread = float4 of cols, k-chunk 64; grid (3, 64) = 192 blocks; 64-way atomic.
__global__ __launch_bounds__(256)
void k_proj1(const float* __restrict__ hidden,
             const float* __restrict__ Wdkv,
             const float* __restrict__ Wdq,
             const float* __restrict__ Wkr,
             float* __restrict__ ws) {
  const int col4 = blockIdx.x * 256 + threadIdx.x;
  const int k0 = blockIdx.y * 64;
  const float* W; int C4; int wcol4; float* dst;
  if (col4 < 128)      { W = Wdkv; C4 = 128; wcol4 = col4;       dst = ws + WS_CKV; }
  else if (col4 < 512) { W = Wdq;  C4 = 384; wcol4 = col4 - 128; dst = ws + WS_CQ; }
  else if (col4 < 528) { W = Wkr;  C4 = 16;  wcol4 = col4 - 512; dst = ws + WS_KRRAW; }
  else return;
  const float4* wp = (const float4*)W + (size_t)k0 * C4 + wcol4;
  float4 acc[NB] = {};
  #pragma unroll 8
  for (int i = 0; i < 64; ++i) {
    float4 w4 = wp[(size_t)i * C4];
    #pragma unroll
    for (int b = 0; b < NB; ++b) fma4(acc[b], hidden[b*HID + k0 + i], w4);
  }
  #pragma unroll
  for (int b = 0; b < NB; ++b) {
    float* d = dst + b*C4*4 + wcol4*4;
    atomicAdd(d+0, acc[b].x); atomicAdd(d+1, acc[b].y);
    atomicAdd(d+2, acc[b].z); atomicAdd(d+3, acc[b].w);
  }
}

// ---------------- K2: c_Q -> q_C, q_R_raw ------------------------------------
// k-chunk 32; grid (6, 48) = 288 blocks; 48-way atomic.
__global__ __launch_bounds__(256)
void k_proj2(const float* __restrict__ Wuq,
             const float* __restrict__ Wqr,
             float* __restrict__ ws) {
  const int col4 = blockIdx.x * 256 + threadIdx.x;  // < 1536
  const int k0 = blockIdx.y * 32;
  const float* W; int C4; int wcol4; float* dst;
  if (col4 < 1024) { W = Wuq; C4 = 1024; wcol4 = col4;        dst = ws + WS_QC; }
  else             { W = Wqr; C4 = 512;  wcol4 = col4 - 1024; dst = ws + WS_QRRAW; }
  const float4* wp = (const float4*)W + (size_t)k0 * C4 + wcol4;
  const float* act = ws + WS_CQ;
  float4 acc[NB] = {};
  #pragma unroll 8
  for (int i = 0; i < 32; ++i) {
    float4 w4 = wp[(size_t)i * C4];
    #pragma unroll
    for (int b = 0; b < NB; ++b) fma4(acc[b], act[b*CQ + k0 + i], w4);
  }
  #pragma unroll
  for (int b = 0; b < NB; ++b) {
    float* d = dst + b*C4*4 + wcol4*4;
    atomicAdd(d+0, acc[b].x); atomicAdd(d+1, acc[b].y);
    atomicAdd(d+2, acc[b].z); atomicAdd(d+3, acc[b].w);
  }
}

// -------- K3: q_abs = q_C @ W_UK^T per head (×SCALE); RoPE; new cache rows ---
__global__ __launch_bounds__(256)
void k_absorb_rope(const float* __restrict__ Wuk,
                   float* __restrict__ ws,
                   float* __restrict__ out_ckv,
                   float* __restrict__ out_kr) {
  const int bid = blockIdx.x, tid = threadIdx.x;
  if (bid < 256) {
    const int h = bid >> 3, cq = bid & 7;
    __shared__ float qc_s[NB][HD];
    __shared__ float part_s[NB][256];
    for (int e = tid; e < NB*HD; e += 256) {
      int b = e >> 7, d = e & 127;
      qc_s[b][d] = ws[WS_QC + b*HID + h*HD + d];
    }
    __syncthreads();
    const int c = cq*64 + (tid & 63);
    const int dg = tid >> 6;
    const float4* wrow = (const float4*)(Wuk + (size_t)c*(NH*HD) + h*HD + dg*32);
    float acc[NB] = {0,0,0,0};
    #pragma unroll
    for (int d4 = 0; d4 < 8; ++d4) {
      float4 w4 = wrow[d4];
      #pragma unroll
      for (int b = 0; b < NB; ++b)
        acc[b] += dot4(w4, *(const float4*)&qc_s[b][dg*32 + d4*4]);
    }
    #pragma unroll
    for (int b = 0; b < NB; ++b) part_s[b][tid] = acc[b];
    __syncthreads();
    if (tid < 64) {
      #pragma unroll
      for (int b = 0; b < NB; ++b) {
        float v = part_s[b][tid] + part_s[b][tid+64] + part_s[b][tid+128] + part_s[b][tid+192];
        ws[WS_QABS + (size_t)(b*NH + h)*CKV + cq*64 + tid] = v * SCALE_F;
      }
    }
  } else {
    const double LN1E4 = 9.210340371976184;
    for (int pid = tid; pid < NB*NH*32; pid += 256) {
      int b = pid >> 10, rem = pid & 1023, h = rem >> 5, i = rem & 31;
      double ang = 4096.0 * exp(-(double)i / 32.0 * LN1E4);
      float cs = (float)cos(ang), sn = (float)sin(ang);
      float x1 = ws[WS_QRRAW + b*(NH*RD) + h*RD + 2*i];
      float x2 = ws[WS_QRRAW + b*(NH*RD) + h*RD + 2*i + 1];
      ws[WS_QROPE + (b*NH + h)*RD + 2*i]     = (x1*cs - x2*sn) * SCALE_F;
      ws[WS_QROPE + (b*NH + h)*RD + 2*i + 1] = (x1*sn + x2*cs) * SCALE_F;
    }
    if (tid < NB*32) {
      int b = tid >> 5, i = tid & 31;
      double ang = 4096.0 * exp(-(double)i / 32.0 * LN1E4);
      float cs = (float)cos(ang), sn = (float)sin(ang);
      float x1 = ws[WS_KRRAW + b*RD + 2*i];
      float x2 = ws[WS_KRRAW + b*RD + 2*i + 1];
      float o0 = x1*cs - x2*sn, o1 = x1*sn + x2*cs;
      ws[WS_KROPE + b*RD + 2*i]     = o0;
      ws[WS_KROPE + b*RD + 2*i + 1] = o1;
      out_kr[(size_t)b*SK*RD + (size_t)SS*RD + 2*i]     = o0;
      out_kr[(size_t)b*SK*RD + (size_t)SS*RD + 2*i + 1] = o1;
    }
    for (int e = tid; e < NB*CKV; e += 256) {
      int b = e >> 9, cc = e & 511;
      out_ckv[(size_t)b*SK*CKV + (size_t)SS*CKV + cc] = ws[WS_CKV + b*CKV + cc];
    }
  }
}

// ---------------- K4: scores — all 32 heads per block, c-split 2 ------------
// wave: 16 keys; lanes = 4 kq × 16 cg; hg-loop covers 4 head-groups of 8.
// cs=0: ckv c[0,256); cs=1: ckv c[256,512) + rope. 2-way atomicAdd into
// zeroed WS_SCORES. grid (65, 2, 4) = 520 blocks.
__global__ __launch_bounds__(256)
void k_scores(const float* __restrict__ kv_cache,
              const float* __restrict__ kr_cache,
              float* __restrict__ ws) {
  const int tid = threadIdx.x;
  const int wid = tid >> 6, lane = tid & 63;
  const int kq = lane >> 4, cg = lane & 15;
  const int b  = blockIdx.z;
  const int cs = blockIdx.y;
  const int kw0 = blockIdx.x * 64 + wid * 16;
  const int coff = cs * 256 + cg * 4;

  const float* ckv_base[4];
  const float* kr_base[4];
  #pragma unroll
  for (int t = 0; t < 4; ++t) {
    int k = kw0 + t*4 + kq;
    if (k < SS)       { ckv_base[t] = kv_cache + ((size_t)b*SS + k)*CKV + coff;
                        kr_base[t]  = kr_cache + ((size_t)b*SS + k)*RD + cg*4; }
    else if (k == SS) { ckv_base[t] = ws + WS_CKV + b*CKV + coff;
                        kr_base[t]  = ws + WS_KROPE + b*RD + cg*4; }
    else              { ckv_base[t] = ws + WS_CKV + coff;      // dummy; store guarded
                        kr_base[t]  = ws + WS_KROPE + cg*4; }
  }
  for (int hg = 0; hg < 4; ++hg) {
    const int h0 = hg * 8;
    const size_t qbase  = WS_QABS  + (size_t)(b*NH + h0)*CKV + coff;
    const size_t qrbase = WS_QROPE + (size_t)(b*NH + h0)*RD  + cg*4;
    float acc[8][4];
    #pragma unroll
    for (int h = 0; h < 8; ++h)
      #pragma unroll
      for (int t = 0; t < 4; ++t) acc[h][t] = 0.f;
    #pragma unroll
    for (int p = 0; p < 4; ++p) {
      float4 kv4[4], q4[8];
      #pragma unroll
      for (int t = 0; t < 4; ++t) kv4[t] = *(const float4*)(ckv_base[t] + p*64);
      #pragma unroll
      for (int h = 0; h < 8; ++h) q4[h] = *(const float4*)(ws + qbase + (size_t)h*CKV + p*64);
      #pragma unroll
      for (int h = 0; h < 8; ++h)
        #pragma unroll
        for (int t = 0; t < 4; ++t)
          acc[h][t] += dot4(q4[h], kv4[t]);
    }
    if (cs) {  // rope tail (64 extra dims)
      float4 kv4[4], q4[8];
      #pragma unroll
      for (int t = 0; t < 4; ++t) kv4[t] = *(const float4*)(kr_base[t]);
      #pragma unroll
      for (int h = 0; h < 8; ++h) q4[h] = *(const float4*)(ws + qrbase + (size_t)h*RD);
      #pragma unroll
      for (int h = 0; h < 8; ++h)
        #pragma unroll
        for (int t = 0; t < 4; ++t)
          acc[h][t] += dot4(q4[h], kv4[t]);
    }
    #pragma unroll
    for (int h = 0; h < 8; ++h) {
      #pragma unroll
      for (int t = 0; t < 4; ++t) {
        float v = acc[h][t];
        v += __shfl_xor(v, 1);
        v += __shfl_xor(v, 2);
        v += __shfl_xor(v, 4);
        v += __shfl_xor(v, 8);
        if (cg == h) {
          int k = kw0 + t*4 + kq;
          if (k < SK)
            atomicAdd(ws + WS_SCORES + (size_t)(b*NH + h0 + h)*SKP + k, v);
        }
      }
    }
  }
}

// ---------------- K5: row softmax over SK (applies mask) --------------------
__global__ __launch_bounds__(256)
void k_softmax(const float* __restrict__ mask, float* __restrict__ ws) {
  __shared__ float red[256];
  const int tid = threadIdx.x;
  const int b = blockIdx.x >> 5;
  float* s = ws + WS_SCORES + (size_t)blockIdx.x * SKP;
  const float* mrow = mask + (size_t)b * SK;
  float v[17];
  float m = -INFINITY;
  #pragma unroll
  for (int r = 0; r < 17; ++r) {
    int k = tid + r*256;
    v[r] = (k < SK) ? (s[k] + mrow[k] * (-1e9f)) : -INFINITY;
    m = fmaxf(m, v[r]);
  }
  red[tid] = m; __syncthreads();
  for (int st = 128; st > 0; st >>= 1) {
    if (tid < st) red[tid] = fmaxf(red[tid], red[tid+st]);
    __syncthreads();
  }
  m = red[0]; __syncthreads();
  float e[17];
  float l = 0.f;
  #pragma unroll
  for (int r = 0; r < 17; ++r) {
    int k = tid + r*256;
    e[r] = (k < SK) ? __expf(v[r] - m) : 0.f;
    l += e[r];
  }
  red[tid] = l; __syncthreads();
  for (int st = 128; st > 0; st >>= 1) {
    if (tid < st) red[tid] += red[tid+st];
    __syncthreads();
  }
  float inv = 1.f / red[0];
  #pragma unroll
  for (int r = 0; r < 17; ++r) {
    int k = tid + r*256;
    if (k < SK) s[k] = e[r] * inv;
  }
}

// ---------------- K6: o_latent = probs @ c_KV — all 32 heads per block ------
// grid (16 k-chunks × 8 c-ranges × 4 b) = 512 blocks; 256-key chunks;
// thread = (head-pair hg, c4); 16-way atomics into WS_OLAT.
__global__ __launch_bounds__(256)
void k_pv(const float* __restrict__ kv_cache, float* __restrict__ ws) {
  const int tid = threadIdx.x;
  const int c4 = tid & 15, hg = tid >> 4;      // hg 0..15; heads hg, hg+16
  const int b  = blockIdx.z;
  const int c  = blockIdx.y * 64 + c4 * 4;
  const int k0 = blockIdx.x * 256;
  const float* kvp = kv_cache + ((size_t)b*SS + k0)*CKV + c;
  const float* pa = ws + WS_SCORES + (size_t)(b*NH + hg)*SKP + k0;
  const float* pb = ws + WS_SCORES + (size_t)(b*NH + hg + 16)*SKP + k0;
  float4 acc0 = {}, acc1 = {};
  #pragma unroll 2
  for (int kk = 0; kk < 256; kk += 4) {
    float4 p4a = *(const float4*)(pa + kk);
    float4 p4b = *(const float4*)(pb + kk);
    float4 kv4[4];
    #pragma unroll
    for (int j = 0; j < 4; ++j)
      kv4[j] = *(const float4*)(kvp + (size_t)(kk + j)*CKV);
    fma4(acc0, p4a.x, kv4[0]); fma4(acc1, p4b.x, kv4[0]);
    fma4(acc0, p4a.y, kv4[1]); fma4(acc1, p4b.y, kv4[1]);
    fma4(acc0, p4a.z, kv4[2]); fma4(acc1, p4b.z, kv4[2]);
    fma4(acc0, p4a.w, kv4[3]); fma4(acc1, p4b.w, kv4[3]);
  }
  if (blockIdx.x == 15) {  // tail key k == SS
    float4 kv = *(const float4*)(ws + WS_CKV + b*CKV + c);
    fma4(acc0, pa[SS - k0], kv);
    fma4(acc1, pb[SS - k0], kv);
  }
  float* d0 = ws + WS_OLAT + (size_t)(b*NH + hg)*CKV + c;
  float* d1 = ws + WS_OLAT + (size_t)(b*NH + hg + 16)*CKV + c;
  atomicAdd(d0+0, acc0.x); atomicAdd(d0+1, acc0.y);
  atomicAdd(d0+2, acc0.z); atomicAdd(d0+3, acc0.w);
  atomicAdd(d1+0, acc1.x); atomicAdd(d1+1, acc1.y);
  atomicAdd(d1+2, acc1.z); atomicAdd(d1+3, acc1.w);
}

// ---------------- K7: attn = o_latent @ W_UV (block-diagonal per head) ------
__global__ __launch_bounds__(256)
void k_uv(const float* __restrict__ Wuv, float* __restrict__ ws) {
  const int col4 = blockIdx.x * 256 + threadIdx.x;  // < 1024
  const int h = col4 >> 5;
  const int k0 = blockIdx.y * 16;
  const float4* wp = (const float4*)Wuv + (size_t)k0 * 1024 + col4;
  float4 acc[NB] = {};
  #pragma unroll 4
  for (int i = 0; i < 16; ++i) {
    float4 w4 = wp[(size_t)i * 1024];
    #pragma unroll
    for (int b = 0; b < NB; ++b)
      fma4(acc[b], ws[WS_OLAT + (size_t)(b*NH + h)*CKV + k0 + i], w4);
  }
  #pragma unroll
  for (int b = 0; b < NB; ++b) {
    float* d = ws + WS_ATTN + b*HID + col4*4;
    atomicAdd(d+0, acc[b].x); atomicAdd(d+1, acc[b].y);
    atomicAdd(d+2, acc[b].z); atomicAdd(d+3, acc[b].w);
  }
}

// ---------------- K8: out = attn @ W_O — k-chunk 64; grid (4,64) ------------
__global__ __launch_bounds__(256)
void k_wo(const float* __restrict__ Wo, const float* __restrict__ ws,
          float* __restrict__ out) {
  const int col4 = blockIdx.x * 256 + threadIdx.x;  // < 1024
  const int k0 = blockIdx.y * 64;
  const float4* wp = (const float4*)Wo + (size_t)k0 * 1024 + col4;
  float4 acc[NB] = {};
  #pragma unroll 8
  for (int i = 0; i < 64; ++i) {
    float4 w4 = wp[(size_t)i * 1024];
    #pragma unroll
    for (int b = 0; b < NB; ++b)
      fma4(acc[b], ws[WS_ATTN + b*HID + k0 + i], w4);
  }
  #pragma unroll
  for (int b = 0; b < NB; ++b) {
    float* d = out + b*HID + col4*4;
    atomicAdd(d+0, acc[b].x); atomicAdd(d+1, acc[b].y);
    atomicAdd(d+2, acc[b].z); atomicAdd(d+3, acc[b].w);
  }
}

// ---------------- K9: cache copy (rows 0..4095) ------------------------------
__global__ __launch_bounds__(256)
void k_copy(const float4* __restrict__ src_ckv,
            const float4* __restrict__ src_kr,
            float4* __restrict__ dst_ckv,
            float4* __restrict__ dst_kr) {
  const int bx = blockIdx.x;
  if (bx < 8192) {
    int b = bx >> 11;
    int idx = (bx & 2047) * 256 + threadIdx.x;
    dst_ckv[(size_t)b*(SK*CKV/4) + idx] = src_ckv[(size_t)b*(SS*CKV/4) + idx];
  } else {
    int bx2 = bx - 8192;
    int b = bx2 >> 8;
    int idx = (bx2 & 255) * 256 + threadIdx.x;
    dst_kr[(size_t)b*(SK*RD/4) + idx] = src_kr[(size_t)b*(SS*RD/4) + idx];
  }
}

extern "C" void kernel_launch(void* const* d_in, const int* in_sizes, int n_in,
                              void* d_out, int out_size, void* d_ws, size_t ws_size,
                              hipStream_t stream) {
  (void)in_sizes; (void)n_in; (void)out_size; (void)ws_size;
  const float* hidden = (const float*)d_in[0];
  const float* mask   = (const float*)d_in[1];
  const float* ckv_c  = (const float*)d_in[2];
  const float* kr_c   = (const float*)d_in[3];
  const float* Wdkv   = (const float*)d_in[4];
  const float* Wuk    = (const float*)d_in[5];
  const float* Wuv    = (const float*)d_in[6];
  const float* Wdq    = (const float*)d_in[7];
  const float* Wuq    = (const float*)d_in[8];
  const float* Wqr    = (const float*)d_in[9];
  const float* Wkr    = (const float*)d_in[10];
  const float* Wo     = (const float*)d_in[11];
  float* out = (float*)d_out;
  float* ws  = (float*)d_ws;
  float* out_ckv = out + NB*HID;
  float* out_kr  = out + NB*HID + (size_t)NB*SK*CKV;

  hipMemsetAsync(ws, 0, (size_t)WS_ZERO_N * sizeof(float), stream);
  hipMemsetAsync(ws + WS_SCORES, 0, (size_t)NB*NH*SKP * sizeof(float), stream);
  hipMemsetAsync(out, 0, (size_t)NB * HID * sizeof(float), stream);

  k_copy<<<9216, 256, 0, stream>>>((const float4*)ckv_c, (const float4*)kr_c,
                                   (float4*)out_ckv, (float4*)out_kr);
  k_proj1<<<dim3(3, 64), 256, 0, stream>>>(hidden, Wdkv, Wdq, Wkr, ws);
  k_proj2<<<dim3(6, 48), 256, 0, stream>>>(Wuq, Wqr, ws);
  k_absorb_rope<<<257, 256, 0, stream>>>(Wuk, ws, out_ckv, out_kr);
  k_scores<<<dim3(65, 2, 4), 256, 0, stream>>>(ckv_c, kr_c, ws);
  k_softmax<<<NB*NH, 256, 0, stream>>>(mask, ws);
  k_pv<<<dim3(16, 8, 4), 256, 0, stream>>>(ckv_c, ws);
  k_uv<<<dim3(4, 32), 256, 0, stream>>>(Wuv, ws);
  k_wo<<<dim3(4, 64), 256, 0, stream>>>(Wo, ws, out);
}

// Round 5
// 194.982 us; speedup vs baseline: 1.3442x; 1.1203x over previous
//
#include <hip/hip_runtime.h>
#include <math.h>

#define NB 4
#define HID 4096
#define CKV 512
#define CQ 1536
#define NH 32
#define HD 128
#define RD 64
#define SS 4096
#define SK 4097
#define SKP 4100  // padded scores row stride (float4-aligned)

#define SCALE_F 0.07216878364870322f  // 1/sqrt(192)

// workspace offsets (floats) — [0, WS_ZERO_N) memset to 0 each call
enum : int {
  WS_CKV    = 0,                       // [NB][CKV]      (zeroed, atomic)
  WS_CQ     = WS_CKV + NB*CKV,         // [NB][CQ]       (zeroed, atomic)
  WS_KRRAW  = WS_CQ + NB*CQ,           // [NB][RD]       (zeroed, atomic)
  WS_QC     = WS_KRRAW + NB*RD,        // [NB][HID]      (zeroed, atomic)
  WS_QRRAW  = WS_QC + NB*HID,          // [NB][NH*RD]    (zeroed, atomic)
  WS_OLAT   = WS_QRRAW + NB*NH*RD,     // [NB][NH][CKV]  (zeroed, atomic)
  WS_ATTN   = WS_OLAT + NB*NH*CKV,     // [NB][HID]      (zeroed, atomic)
  WS_ZERO_N = WS_ATTN + NB*HID,        // = 114944
  WS_QABS   = WS_ZERO_N,               // [NB][NH][CKV]  (pre-scaled)
  WS_QROPE  = WS_QABS + NB*NH*CKV,     // [NB][NH][RD]   (pre-scaled)
  WS_KROPE  = WS_QROPE + NB*NH*RD,     // [NB][RD]
  WS_SCORES = WS_KROPE + NB*RD,        // [NB][NH][SKP]  (zeroed separately, atomic)
  WS_TOTAL  = WS_SCORES + NB*NH*SKP
};

__device__ inline void fma4(float4& a, float s, const float4& v) {
  a.x += s*v.x; a.y += s*v.y; a.z += s*v.z; a.w += s*v.w;
}
__device__ inline float dot4(const float4& a, const float4& b) {
  return a.x*b.x + a.y*b.y + a.z*b.z + a.w*b.w;
}

// ---------------- K1: hidden -> c_KV, c_Q, k_R_raw ---------------------------
__global__ __launch_bounds__(256)
void k_proj1(const float* __restrict__ hidden,
             const float* __restrict__ Wdkv,
             const float* __restrict__ Wdq,
             const float* __restrict__ Wkr,
             float* __restrict__ ws) {
  const int col4 = blockIdx.x * 256 + threadIdx.x;
  const int k0 = blockIdx.y * 64;
  const float* W; int C4; int wcol4; float* dst;
  if (col4 < 128)      { W = Wdkv; C4 = 128; wcol4 = col4;       dst = ws + WS_CKV; }
  else if (col4 < 512) { W = Wdq;  C4 = 384; wcol4 = col4 - 128; dst = ws + WS_CQ; }
  else if (col4 < 528) { W = Wkr;  C4 = 16;  wcol4 = col4 - 512; dst = ws + WS_KRRAW; }
  else return;
  const float4* wp = (const float4*)W + (size_t)k0 * C4 + wcol4;
  float4 acc[NB] = {};
  #pragma unroll 8
  for (int i = 0; i < 64; ++i) {
    float4 w4 = wp[(size_t)i * C4];
    #pragma unroll
    for (int b = 0; b < NB; ++b) fma4(acc[b], hidden[b*HID + k0 + i], w4);
  }
  #pragma unroll
  for (int b = 0; b < NB; ++b) {
    float* d = dst + b*C4*4 + wcol4*4;
    atomicAdd(d+0, acc[b].x); atomicAdd(d+1, acc[b].y);
    atomicAdd(d+2, acc[b].z); atomicAdd(d+3, acc[b].w);
  }
}

// ---------------- K2: c_Q -> q_C, q_R_raw ------------------------------------
__global__ __launch_bounds__(256)
void k_proj2(const float* __restrict__ Wuq,
             const float* __restrict__ Wqr,
             float* __restrict__ ws) {
  const int col4 = blockIdx.x * 256 + threadIdx.x;  // < 1536
  const int k0 = blockIdx.y * 32;
  const float* W; int C4; int wcol4; float* dst;
  if (col4 < 1024) { W = Wuq; C4 = 1024; wcol4 = col4;        dst = ws + WS_QC; }
  else             { W = Wqr; C4 = 512;  wcol4 = col4 - 1024; dst = ws + WS_QRRAW; }
  const float4* wp = (const float4*)W + (size_t)k0 * C4 + wcol4;
  const float* act = ws + WS_CQ;
  float4 acc[NB] = {};
  #pragma unroll 8
  for (int i = 0; i < 32; ++i) {
    float4 w4 = wp[(size_t)i * C4];
    #pragma unroll
    for (int b = 0; b < NB; ++b) fma4(acc[b], act[b*CQ + k0 + i], w4);
  }
  #pragma unroll
  for (int b = 0; b < NB; ++b) {
    float* d = dst + b*C4*4 + wcol4*4;
    atomicAdd(d+0, acc[b].x); atomicAdd(d+1, acc[b].y);
    atomicAdd(d+2, acc[b].z); atomicAdd(d+3, acc[b].w);
  }
}

// -------- K3: q_abs = q_C @ W_UK^T per head (×SCALE); RoPE; new cache rows ---
__global__ __launch_bounds__(256)
void k_absorb_rope(const float* __restrict__ Wuk,
                   float* __restrict__ ws,
                   float* __restrict__ out_ckv,
                   float* __restrict__ out_kr) {
  const int bid = blockIdx.x, tid = threadIdx.x;
  if (bid < 256) {
    const int h = bid >> 3, cq = bid & 7;
    __shared__ float qc_s[NB][HD];
    __shared__ float part_s[NB][256];
    for (int e = tid; e < NB*HD; e += 256) {
      int b = e >> 7, d = e & 127;
      qc_s[b][d] = ws[WS_QC + b*HID + h*HD + d];
    }
    __syncthreads();
    const int c = cq*64 + (tid & 63);
    const int dg = tid >> 6;
    const float4* wrow = (const float4*)(Wuk + (size_t)c*(NH*HD) + h*HD + dg*32);
    float acc[NB] = {0,0,0,0};
    #pragma unroll
    for (int d4 = 0; d4 < 8; ++d4) {
      float4 w4 = wrow[d4];
      #pragma unroll
      for (int b = 0; b < NB; ++b)
        acc[b] += dot4(w4, *(const float4*)&qc_s[b][dg*32 + d4*4]);
    }
    #pragma unroll
    for (int b = 0; b < NB; ++b) part_s[b][tid] = acc[b];
    __syncthreads();
    if (tid < 64) {
      #pragma unroll
      for (int b = 0; b < NB; ++b) {
        float v = part_s[b][tid] + part_s[b][tid+64] + part_s[b][tid+128] + part_s[b][tid+192];
        ws[WS_QABS + (size_t)(b*NH + h)*CKV + cq*64 + tid] = v * SCALE_F;
      }
    }
  } else {
    const double LN1E4 = 9.210340371976184;
    for (int pid = tid; pid < NB*NH*32; pid += 256) {
      int b = pid >> 10, rem = pid & 1023, h = rem >> 5, i = rem & 31;
      double ang = 4096.0 * exp(-(double)i / 32.0 * LN1E4);
      float cs = (float)cos(ang), sn = (float)sin(ang);
      float x1 = ws[WS_QRRAW + b*(NH*RD) + h*RD + 2*i];
      float x2 = ws[WS_QRRAW + b*(NH*RD) + h*RD + 2*i + 1];
      ws[WS_QROPE + (b*NH + h)*RD + 2*i]     = (x1*cs - x2*sn) * SCALE_F;
      ws[WS_QROPE + (b*NH + h)*RD + 2*i + 1] = (x1*sn + x2*cs) * SCALE_F;
    }
    if (tid < NB*32) {
      int b = tid >> 5, i = tid & 31;
      double ang = 4096.0 * exp(-(double)i / 32.0 * LN1E4);
      float cs = (float)cos(ang), sn = (float)sin(ang);
      float x1 = ws[WS_KRRAW + b*RD + 2*i];
      float x2 = ws[WS_KRRAW + b*RD + 2*i + 1];
      float o0 = x1*cs - x2*sn, o1 = x1*sn + x2*cs;
      ws[WS_KROPE + b*RD + 2*i]     = o0;
      ws[WS_KROPE + b*RD + 2*i + 1] = o1;
      out_kr[(size_t)b*SK*RD + (size_t)SS*RD + 2*i]     = o0;
      out_kr[(size_t)b*SK*RD + (size_t)SS*RD + 2*i + 1] = o1;
    }
    for (int e = tid; e < NB*CKV; e += 256) {
      int b = e >> 9, cc = e & 511;
      out_ckv[(size_t)b*SK*CKV + (size_t)SS*CKV + cc] = ws[WS_CKV + b*CKV + cc];
    }
  }
}

// ---------------- K4: scores — LDS-staged q (swizzled), streamed kv ---------
// grid (65, 2, 4): 64 keys × 32 heads × c-half (cs=1 adds rope).
// wave: 16 keys; lane = kq*16 + cg; 2-key unroll; shfl butterfly over cg;
// 2-way atomicAdd into zeroed WS_SCORES.
__global__ __launch_bounds__(256)
void k_scores(const float* __restrict__ kv_cache,
              const float* __restrict__ kr_cache,
              float* __restrict__ ws) {
  __shared__ float4 q_s[32*65];    // swizzled: slot f stored at f ^ (f>>2)
  __shared__ float4 qr_s[32*17];   // rope (cs=1 only)
  const int tid = threadIdx.x;
  const int b  = blockIdx.z;
  const int cs = blockIdx.y;
  {
    const float4* qabs4 = (const float4*)(ws + WS_QABS) + (size_t)(b*NH)*128;
    for (int e = tid; e < 32*64; e += 256) {
      int h = e >> 6, f = e & 63;
      q_s[h*65 + (f ^ (f >> 2))] = qabs4[h*128 + cs*64 + f];
    }
    if (cs) {
      const float4* qr4 = (const float4*)(ws + WS_QROPE) + (size_t)(b*NH)*16;
      for (int e = tid; e < 32*16; e += 256) {
        int h = e >> 4, s = e & 15;
        qr_s[h*17 + s] = qr4[h*16 + s];
      }
    }
  }
  __syncthreads();
  const int lane = tid & 63, wid = tid >> 6;
  const int cg = lane & 15, kq = lane >> 4;
  const int sw = (cg << 2) ^ cg;
  const int kbase = blockIdx.x * 64 + wid * 16;

  #pragma unroll
  for (int half = 0; half < 2; ++half) {
    const int ka = kbase + half*8 + kq;
    const int kb = ka + 4;
    const float4* ra =
        (ka < SS)  ? (const float4*)(kv_cache + ((size_t)b*SS + ka)*CKV)
      : (ka == SS) ? (const float4*)(ws + WS_CKV + b*CKV)
                   : (const float4*)(ws + WS_CKV);
    const float4* rb =
        (kb < SS)  ? (const float4*)(kv_cache + ((size_t)b*SS + kb)*CKV)
      : (kb == SS) ? (const float4*)(ws + WS_CKV + b*CKV)
                   : (const float4*)(ws + WS_CKV);
    float4 kva[4], kvb[4];
    #pragma unroll
    for (int j = 0; j < 4; ++j) {
      kva[j] = ra[cs*64 + cg*4 + j];
      kvb[j] = rb[cs*64 + cg*4 + j];
    }
    float4 kra = make_float4(0,0,0,0), krb = make_float4(0,0,0,0);
    if (cs) {
      const float4* rra =
          (ka < SS)  ? (const float4*)(kr_cache + ((size_t)b*SS + ka)*RD)
        : (ka == SS) ? (const float4*)(ws + WS_KROPE + b*RD)
                     : (const float4*)(ws + WS_KROPE);
      const float4* rrb =
          (kb < SS)  ? (const float4*)(kr_cache + ((size_t)b*SS + kb)*RD)
        : (kb == SS) ? (const float4*)(ws + WS_KROPE + b*RD)
                     : (const float4*)(ws + WS_KROPE);
      kra = rra[cg];
      krb = rrb[cg];
    }
    float accA[32], accB[32];
    #pragma unroll
    for (int h = 0; h < 32; ++h) {
      const float4* qrow = &q_s[h*65];
      float4 q0 = qrow[sw], q1 = qrow[sw^1], q2 = qrow[sw^2], q3 = qrow[sw^3];
      accA[h] = dot4(q0,kva[0]) + dot4(q1,kva[1]) + dot4(q2,kva[2]) + dot4(q3,kva[3]);
      accB[h] = dot4(q0,kvb[0]) + dot4(q1,kvb[1]) + dot4(q2,kvb[2]) + dot4(q3,kvb[3]);
      if (cs) {
        float4 qr = qr_s[h*17 + cg];
        accA[h] += dot4(qr, kra);
        accB[h] += dot4(qr, krb);
      }
    }
    #pragma unroll
    for (int h = 0; h < 32; ++h) {
      float va = accA[h], vb = accB[h];
      va += __shfl_xor(va, 1); vb += __shfl_xor(vb, 1);
      va += __shfl_xor(va, 2); vb += __shfl_xor(vb, 2);
      va += __shfl_xor(va, 4); vb += __shfl_xor(vb, 4);
      va += __shfl_xor(va, 8); vb += __shfl_xor(vb, 8);
      if (cg == (h & 15)) {
        float* srow = ws + WS_SCORES + (size_t)(b*NH + h)*SKP;
        if (ka <= SS) atomicAdd(srow + ka, va);
        if (kb <= SS) atomicAdd(srow + kb, vb);
      }
    }
  }
}

// ---------------- K5: row softmax over SK (applies mask) --------------------
__global__ __launch_bounds__(256)
void k_softmax(const float* __restrict__ mask, float* __restrict__ ws) {
  __shared__ float red[256];
  const int tid = threadIdx.x;
  const int b = blockIdx.x >> 5;
  float* s = ws + WS_SCORES + (size_t)blockIdx.x * SKP;
  const float* mrow = mask + (size_t)b * SK;
  float v[17];
  float m = -INFINITY;
  #pragma unroll
  for (int r = 0; r < 17; ++r) {
    int k = tid + r*256;
    v[r] = (k < SK) ? (s[k] + mrow[k] * (-1e9f)) : -INFINITY;
    m = fmaxf(m, v[r]);
  }
  red[tid] = m; __syncthreads();
  for (int st = 128; st > 0; st >>= 1) {
    if (tid < st) red[tid] = fmaxf(red[tid], red[tid+st]);
    __syncthreads();
  }
  m = red[0]; __syncthreads();
  float e[17];
  float l = 0.f;
  #pragma unroll
  for (int r = 0; r < 17; ++r) {
    int k = tid + r*256;
    e[r] = (k < SK) ? __expf(v[r] - m) : 0.f;
    l += e[r];
  }
  red[tid] = l; __syncthreads();
  for (int st = 128; st > 0; st >>= 1) {
    if (tid < st) red[tid] += red[tid+st];
    __syncthreads();
  }
  float inv = 1.f / red[0];
  #pragma unroll
  for (int r = 0; r < 17; ++r) {
    int k = tid + r*256;
    if (k < SK) s[k] = e[r] * inv;
  }
}

// ---------------- K6: o_latent = probs @ c_KV — all 32 heads per block ------
__global__ __launch_bounds__(256)
void k_pv(const float* __restrict__ kv_cache, float* __restrict__ ws) {
  const int tid = threadIdx.x;
  const int c4 = tid & 15, hg = tid >> 4;      // hg 0..15; heads hg, hg+16
  const int b  = blockIdx.z;
  const int c  = blockIdx.y * 64 + c4 * 4;
  const int k0 = blockIdx.x * 256;
  const float* kvp = kv_cache + ((size_t)b*SS + k0)*CKV + c;
  const float* pa = ws + WS_SCORES + (size_t)(b*NH + hg)*SKP + k0;
  const float* pb = ws + WS_SCORES + (size_t)(b*NH + hg + 16)*SKP + k0;
  float4 acc0 = {}, acc1 = {};
  #pragma unroll 2
  for (int kk = 0; kk < 256; kk += 4) {
    float4 p4a = *(const float4*)(pa + kk);
    float4 p4b = *(const float4*)(pb + kk);
    float4 kv4[4];
    #pragma unroll
    for (int j = 0; j < 4; ++j)
      kv4[j] = *(const float4*)(kvp + (size_t)(kk + j)*CKV);
    fma4(acc0, p4a.x, kv4[0]); fma4(acc1, p4b.x, kv4[0]);
    fma4(acc0, p4a.y, kv4[1]); fma4(acc1, p4b.y, kv4[1]);
    fma4(acc0, p4a.z, kv4[2]); fma4(acc1, p4b.z, kv4[2]);
    fma4(acc0, p4a.w, kv4[3]); fma4(acc1, p4b.w, kv4[3]);
  }
  if (blockIdx.x == 15) {  // tail key k == SS
    float4 kv = *(const float4*)(ws + WS_CKV + b*CKV + c);
    fma4(acc0, pa[SS - k0], kv);
    fma4(acc1, pb[SS - k0], kv);
  }
  float* d0 = ws + WS_OLAT + (size_t)(b*NH + hg)*CKV + c;
  float* d1 = ws + WS_OLAT + (size_t)(b*NH + hg + 16)*CKV + c;
  atomicAdd(d0+0, acc0.x); atomicAdd(d0+1, acc0.y);
  atomicAdd(d0+2, acc0.z); atomicAdd(d0+3, acc0.w);
  atomicAdd(d1+0, acc1.x); atomicAdd(d1+1, acc1.y);
  atomicAdd(d1+2, acc1.z); atomicAdd(d1+3, acc1.w);
}

// ---------------- K7: attn = o_latent @ W_UV (block-diagonal per head) ------
__global__ __launch_bounds__(256)
void k_uv(const float* __restrict__ Wuv, float* __restrict__ ws) {
  const int col4 = blockIdx.x * 256 + threadIdx.x;  // < 1024
  const int h = col4 >> 5;
  const int k0 = blockIdx.y * 16;
  const float4* wp = (const float4*)Wuv + (size_t)k0 * 1024 + col4;
  float4 acc[NB] = {};
  #pragma unroll 4
  for (int i = 0; i < 16; ++i) {
    float4 w4 = wp[(size_t)i * 1024];
    #pragma unroll
    for (int b = 0; b < NB; ++b)
      fma4(acc[b], ws[WS_OLAT + (size_t)(b*NH + h)*CKV + k0 + i], w4);
  }
  #pragma unroll
  for (int b = 0; b < NB; ++b) {
    float* d = ws + WS_ATTN + b*HID + col4*4;
    atomicAdd(d+0, acc[b].x); atomicAdd(d+1, acc[b].y);
    atomicAdd(d+2, acc[b].z); atomicAdd(d+3, acc[b].w);
  }
}

// ---------------- K8: out = attn @ W_O — k-chunk 64; grid (4,64) ------------
__global__ __launch_bounds__(256)
void k_wo(const float* __restrict__ Wo, const float* __restrict__ ws,
          float* __restrict__ out) {
  const int col4 = blockIdx.x * 256 + threadIdx.x;  // < 1024
  const int k0 = blockIdx.y * 64;
  const float4* wp = (const float4*)Wo + (size_t)k0 * 1024 + col4;
  float4 acc[NB] = {};
  #pragma unroll 8
  for (int i = 0; i < 64; ++i) {
    float4 w4 = wp[(size_t)i * 1024];
    #pragma unroll
    for (int b = 0; b < NB; ++b)
      fma4(acc[b], ws[WS_ATTN + b*HID + k0 + i], w4);
  }
  #pragma unroll
  for (int b = 0; b < NB; ++b) {
    float* d = out + b*HID + col4*4;
    atomicAdd(d+0, acc[b].x); atomicAdd(d+1, acc[b].y);
    atomicAdd(d+2, acc[b].z); atomicAdd(d+3, acc[b].w);
  }
}

// ---------------- K9: cache copy (rows 0..4095) ------------------------------
__global__ __launch_bounds__(256)
void k_copy(const float4* __restrict__ src_ckv,
            const float4* __restrict__ src_kr,
            float4* __restrict__ dst_ckv,
            float4* __restrict__ dst_kr) {
  const int bx = blockIdx.x;
  if (bx < 8192) {
    int b = bx >> 11;
    int idx = (bx & 2047) * 256 + threadIdx.x;
    dst_ckv[(size_t)b*(SK*CKV/4) + idx] = src_ckv[(size_t)b*(SS*CKV/4) + idx];
  } else {
    int bx2 = bx - 8192;
    int b = bx2 >> 8;
    int idx = (bx2 & 255) * 256 + threadIdx.x;
    dst_kr[(size_t)b*(SK*RD/4) + idx] = src_kr[(size_t)b*(SS*RD/4) + idx];
  }
}

extern "C" void kernel_launch(void* const* d_in, const int* in_sizes, int n_in,
                              void* d_out, int out_size, void* d_ws, size_t ws_size,
                              hipStream_t stream) {
  (void)in_sizes; (void)n_in; (void)out_size; (void)ws_size;
  const float* hidden = (const float*)d_in[0];
  const float* mask   = (const float*)d_in[1];
  const float* ckv_c  = (const float*)d_in[2];
  const float* kr_c   = (const float*)d_in[3];
  const float* Wdkv   = (const float*)d_in[4];
  const float* Wuk    = (const float*)d_in[5];
  const float* Wuv    = (const float*)d_in[6];
  const float* Wdq    = (const float*)d_in[7];
  const float* Wuq    = (const float*)d_in[8];
  const float* Wqr    = (const float*)d_in[9];
  const float* Wkr    = (const float*)d_in[10];
  const float* Wo     = (const float*)d_in[11];
  float* out = (float*)d_out;
  float* ws  = (float*)d_ws;
  float* out_ckv = out + NB*HID;
  float* out_kr  = out + NB*HID + (size_t)NB*SK*CKV;

  hipMemsetAsync(ws, 0, (size_t)WS_ZERO_N * sizeof(float), stream);
  hipMemsetAsync(ws + WS_SCORES, 0, (size_t)NB*NH*SKP * sizeof(float), stream);
  hipMemsetAsync(out, 0, (size_t)NB * HID * sizeof(float), stream);

  k_copy<<<9216, 256, 0, stream>>>((const float4*)ckv_c, (const float4*)kr_c,
                                   (float4*)out_ckv, (float4*)out_kr);
  k_proj1<<<dim3(3, 64), 256, 0, stream>>>(hidden, Wdkv, Wdq, Wkr, ws);
  k_proj2<<<dim3(6, 48), 256, 0, stream>>>(Wuq, Wqr, ws);
  k_absorb_rope<<<257, 256, 0, stream>>>(Wuk, ws, out_ckv, out_kr);
  k_scores<<<dim3(65, 2, 4), 256, 0, stream>>>(ckv_c, kr_c, ws);
  k_softmax<<<NB*NH, 256, 0, stream>>>(mask, ws);
  k_pv<<<dim3(16, 8, 4), 256, 0, stream>>>(ckv_c, ws);
  k_uv<<<dim3(4, 32), 256, 0, stream>>>(Wuv, ws);
  k_wo<<<dim3(4, 64), 256, 0, stream>>>(Wo, ws, out);
}

// Round 6
// 176.704 us; speedup vs baseline: 1.4832x; 1.1034x over previous
//
#include <hip/hip_runtime.h>
#include <math.h>

#define NB 4
#define HID 4096
#define CKV 512
#define CQ 1536
#define NH 32
#define HD 128
#define RD 64
#define SS 4096
#define SK 4097
#define SKP 4100  // padded scores row stride

#define SCALE_F 0.07216878364870322f  // 1/sqrt(192)

#define NP1 64   // proj1 k-chunks (64 over HID)
#define NP2 24   // proj2 k-chunks (64 over CQ)
#define NPV 16   // pv key-chunks (256 over SS)
#define NUV 32   // uv c-chunks (16 over CKV)
#define NWO 32   // wo k-chunks (128 over HID)

// workspace offsets (floats). NO memset needed — every cell is overwritten
// before read. Partial regions are lifetime-overlapped:
//   WS_A: P1 (proj1..reduce1) then OPART (pv..reduce3)
//   WS_B: P2 (proj2..absorb)  then WOPART (wo..reduce5)
enum : int {
  WS_QABS  = 0,                      // [NB][NH][CKV] pre-scaled
  WS_QROPE = WS_QABS + NB*NH*CKV,    // [NB][NH][RD]  pre-scaled
  WS_KROPE = WS_QROPE + NB*NH*RD,    // [NB][RD]
  WS_CKV   = WS_KROPE + NB*RD,       // [NB][CKV]
  WS_CQ    = WS_CKV + NB*CKV,        // [NB][CQ]
  WS_OLAT  = WS_CQ + NB*CQ,          // [NB][NH][CKV]
  WS_ATTN  = WS_OLAT + NB*NH*CKV,    // [NB][HID]
  WS_SCA   = WS_ATTN + NB*HID,       // [NB][NH][SKP] (cs=0 partial -> probs)
  WS_SCB   = WS_SCA + NB*NH*SKP,     // [NB][NH][SKP] (cs=1 partial)
  WS_A     = WS_SCB + NB*NH*SKP,     // max(P1 540672, OPART 1048576)
  WS_B     = WS_A + NPV*NB*NH*CKV,   // max(P2 589824, WOPART 524288)
  WS_C     = WS_B + NP2*NB*6144,     // UVPART 32*16384 = 524288
  WS_TOTAL = WS_C + NUV*NB*HID       // ~3.4M floats ~= 13.5 MB
};
#define WS_P1     WS_A
#define WS_OPART  WS_A
#define WS_P2     WS_B
#define WS_WOPART WS_B
#define WS_UVPART WS_C

__device__ inline void fma4(float4& a, float s, const float4& v) {
  a.x += s*v.x; a.y += s*v.y; a.z += s*v.z; a.w += s*v.w;
}
__device__ inline float dot4(const float4& a, const float4& b) {
  return a.x*b.x + a.y*b.y + a.z*b.z + a.w*b.w;
}

// ---------------- K1: hidden -> P1 partials (no atomics) ---------------------
// col4: [0,128) c_KV, [128,512) c_Q, [512,528) k_R. grid (3, NP1) = 192 blocks.
__global__ __launch_bounds__(256)
void k_proj1(const float* __restrict__ hidden,
             const float* __restrict__ Wdkv,
             const float* __restrict__ Wdq,
             const float* __restrict__ Wkr,
             float* __restrict__ ws) {
  const int col4 = blockIdx.x * 256 + threadIdx.x;
  if (col4 >= 528) return;
  const int k0 = blockIdx.y * (HID / NP1);
  const float* W; int C4; int wcol4;
  if (col4 < 128)      { W = Wdkv; C4 = 128; wcol4 = col4; }
  else if (col4 < 512) { W = Wdq;  C4 = 384; wcol4 = col4 - 128; }
  else                 { W = Wkr;  C4 = 16;  wcol4 = col4 - 512; }
  const float4* wp = (const float4*)W + (size_t)k0 * C4 + wcol4;
  float4 acc[NB] = {};
  #pragma unroll 8
  for (int i = 0; i < HID / NP1; ++i) {
    float4 w4 = wp[(size_t)i * C4];
    #pragma unroll
    for (int b = 0; b < NB; ++b) fma4(acc[b], hidden[b*HID + k0 + i], w4);
  }
  #pragma unroll
  for (int b = 0; b < NB; ++b)
    *(float4*)(ws + WS_P1 + ((size_t)(blockIdx.y*NB + b)*528 + col4)*4) = acc[b];
}

// ---------------- R1: reduce P1 -> c_KV, c_Q; k_R RoPE; new cache rows -------
__global__ __launch_bounds__(256)
void k_reduce1(float* __restrict__ ws,
               float* __restrict__ out_ckv,
               float* __restrict__ out_kr) {
  const int w = blockIdx.x * 256 + threadIdx.x;  // < 2112
  if (w >= 528*NB) return;
  const int b = w / 528, col4 = w % 528;
  float4 s = {};
  #pragma unroll
  for (int p = 0; p < NP1; ++p) {
    float4 v = *(const float4*)(ws + WS_P1 + ((size_t)(p*NB + b)*528 + col4)*4);
    s.x += v.x; s.y += v.y; s.z += v.z; s.w += v.w;
  }
  if (col4 < 128) {
    *(float4*)(ws + WS_CKV + b*CKV + col4*4) = s;
    *(float4*)(out_ckv + (size_t)b*SK*CKV + (size_t)SS*CKV + col4*4) = s;
  } else if (col4 < 512) {
    *(float4*)(ws + WS_CQ + b*CQ + (col4 - 128)*4) = s;
  } else {
    const int c0 = (col4 - 512) * 4;      // 2 rope pairs per float4
    const double LN1E4 = 9.210340371976184;
    int i0 = c0 >> 1;
    double a0 = 4096.0 * exp(-(double)i0 / 32.0 * LN1E4);
    double a1 = 4096.0 * exp(-(double)(i0 + 1) / 32.0 * LN1E4);
    float c0f = (float)cos(a0), s0f = (float)sin(a0);
    float c1f = (float)cos(a1), s1f = (float)sin(a1);
    float4 o;
    o.x = s.x*c0f - s.y*s0f;  o.y = s.x*s0f + s.y*c0f;
    o.z = s.z*c1f - s.w*s1f;  o.w = s.z*s1f + s.w*c1f;
    *(float4*)(ws + WS_KROPE + b*RD + c0) = o;
    *(float4*)(out_kr + (size_t)b*SK*RD + (size_t)SS*RD + c0) = o;
  }
}

// ---------------- K2: c_Q -> P2 partials (no atomics) ------------------------
// columns: [0,4096) q_C, [4096,6144) q_R_raw. grid (6, NP2) = 144 blocks.
__global__ __launch_bounds__(256)
void k_proj2(const float* __restrict__ Wuq,
             const float* __restrict__ Wqr,
             float* __restrict__ ws) {
  const int col4 = blockIdx.x * 256 + threadIdx.x;  // < 1536
  const int k0 = blockIdx.y * (CQ / NP2);
  const float* W; int C4; int wcol4;
  if (col4 < 1024) { W = Wuq; C4 = 1024; wcol4 = col4; }
  else             { W = Wqr; C4 = 512;  wcol4 = col4 - 1024; }
  const float4* wp = (const float4*)W + (size_t)k0 * C4 + wcol4;
  const float* act = ws + WS_CQ;
  float4 acc[NB] = {};
  #pragma unroll 8
  for (int i = 0; i < CQ / NP2; ++i) {
    float4 w4 = wp[(size_t)i * C4];
    #pragma unroll
    for (int b = 0; b < NB; ++b) fma4(acc[b], act[b*CQ + k0 + i], w4);
  }
  #pragma unroll
  for (int b = 0; b < NB; ++b)
    *(float4*)(ws + WS_P2 + (size_t)(blockIdx.y*NB + b)*6144 + col4*4) = acc[b];
}

// -------- K3: q_abs = q_C @ W_UK^T (×SCALE), P2-reduce fused; q_R RoPE -------
// grid 260: bid<256 compute (h, c-slice); bid 256..259 rope for batch b.
__global__ __launch_bounds__(256)
void k_absorb_rope(const float* __restrict__ Wuk,
                   float* __restrict__ ws) {
  const int bid = blockIdx.x, tid = threadIdx.x;
  if (bid < 256) {
    const int h = bid >> 3, cq = bid & 7;
    __shared__ float qc_s[NB][HD];
    __shared__ float part_s[NB][256];
    for (int e = tid; e < NB*HD; e += 256) {
      int b = e >> 7, d = e & 127;
      float v = 0.f;
      #pragma unroll
      for (int p = 0; p < NP2; ++p)
        v += ws[WS_P2 + (size_t)(p*NB + b)*6144 + h*HD + d];
      qc_s[b][d] = v;
    }
    __syncthreads();
    const int c = cq*64 + (tid & 63);
    const int dg = tid >> 6;
    const float4* wrow = (const float4*)(Wuk + (size_t)c*(NH*HD) + h*HD + dg*32);
    float acc[NB] = {0,0,0,0};
    #pragma unroll
    for (int d4 = 0; d4 < 8; ++d4) {
      float4 w4 = wrow[d4];
      #pragma unroll
      for (int b = 0; b < NB; ++b)
        acc[b] += dot4(w4, *(const float4*)&qc_s[b][dg*32 + d4*4]);
    }
    #pragma unroll
    for (int b = 0; b < NB; ++b) part_s[b][tid] = acc[b];
    __syncthreads();
    if (tid < 64) {
      #pragma unroll
      for (int b = 0; b < NB; ++b) {
        float v = part_s[b][tid] + part_s[b][tid+64] + part_s[b][tid+128] + part_s[b][tid+192];
        ws[WS_QABS + (size_t)(b*NH + h)*CKV + cq*64 + tid] = v * SCALE_F;
      }
    }
  } else {
    const int b = bid - 256;
    const double LN1E4 = 9.210340371976184;
    for (int pid = tid; pid < NH*32; pid += 256) {
      int h = pid >> 5, i = pid & 31;
      float x1 = 0.f, x2 = 0.f;
      #pragma unroll
      for (int p = 0; p < NP2; ++p) {
        const float* base = ws + WS_P2 + (size_t)(p*NB + b)*6144 + 4096 + h*RD + 2*i;
        x1 += base[0]; x2 += base[1];
      }
      double ang = 4096.0 * exp(-(double)i / 32.0 * LN1E4);
      float cs = (float)cos(ang), sn = (float)sin(ang);
      ws[WS_QROPE + (b*NH + h)*RD + 2*i]     = (x1*cs - x2*sn) * SCALE_F;
      ws[WS_QROPE + (b*NH + h)*RD + 2*i + 1] = (x1*sn + x2*cs) * SCALE_F;
    }
  }
}

// ---------------- K4: scores — LDS-staged q, streamed kv, plain stores ------
// grid (65, 2, 4); cs=0 -> SCA (c 0..255), cs=1 -> SCB (c 256..511 + rope).
__global__ __launch_bounds__(256)
void k_scores(const float* __restrict__ kv_cache,
              const float* __restrict__ kr_cache,
              float* __restrict__ ws) {
  __shared__ float4 q_s[32*65];    // swizzled: slot f stored at f ^ (f>>2)
  __shared__ float4 qr_s[32*17];
  const int tid = threadIdx.x;
  const int b  = blockIdx.z;
  const int cs = blockIdx.y;
  {
    const float4* qabs4 = (const float4*)(ws + WS_QABS) + (size_t)(b*NH)*128;
    for (int e = tid; e < 32*64; e += 256) {
      int h = e >> 6, f = e & 63;
      q_s[h*65 + (f ^ (f >> 2))] = qabs4[h*128 + cs*64 + f];
    }
    if (cs) {
      const float4* qr4 = (const float4*)(ws + WS_QROPE) + (size_t)(b*NH)*16;
      for (int e = tid; e < 32*16; e += 256) {
        int h = e >> 4, s = e & 15;
        qr_s[h*17 + s] = qr4[h*16 + s];
      }
    }
  }
  __syncthreads();
  const int lane = tid & 63, wid = tid >> 6;
  const int cg = lane & 15, kq = lane >> 4;
  const int sw = (cg << 2) ^ cg;
  const int kbase = blockIdx.x * 64 + wid * 16;
  float* sbuf = ws + (cs ? WS_SCB : WS_SCA);

  #pragma unroll
  for (int half = 0; half < 2; ++half) {
    const int ka = kbase + half*8 + kq;
    const int kb = ka + 4;
    const float4* ra =
        (ka < SS)  ? (const float4*)(kv_cache + ((size_t)b*SS + ka)*CKV)
      : (ka == SS) ? (const float4*)(ws + WS_CKV + b*CKV)
                   : (const float4*)(ws + WS_CKV);
    const float4* rb =
        (kb < SS)  ? (const float4*)(kv_cache + ((size_t)b*SS + kb)*CKV)
      : (kb == SS) ? (const float4*)(ws + WS_CKV + b*CKV)
                   : (const float4*)(ws + WS_CKV);
    float4 kva[4], kvb[4];
    #pragma unroll
    for (int j = 0; j < 4; ++j) {
      kva[j] = ra[cs*64 + cg*4 + j];
      kvb[j] = rb[cs*64 + cg*4 + j];
    }
    float4 kra = make_float4(0,0,0,0), krb = make_float4(0,0,0,0);
    if (cs) {
      const float4* rra =
          (ka < SS)  ? (const float4*)(kr_cache + ((size_t)b*SS + ka)*RD)
        : (ka == SS) ? (const float4*)(ws + WS_KROPE + b*RD)
                     : (const float4*)(ws + WS_KROPE);
      const float4* rrb =
          (kb < SS)  ? (const float4*)(kr_cache + ((size_t)b*SS + kb)*RD)
        : (kb == SS) ? (const float4*)(ws + WS_KROPE + b*RD)
                     : (const float4*)(ws + WS_KROPE);
      kra = rra[cg];
      krb = rrb[cg];
    }
    float accA[32], accB[32];
    #pragma unroll
    for (int h = 0; h < 32; ++h) {
      const float4* qrow = &q_s[h*65];
      float4 q0 = qrow[sw], q1 = qrow[sw^1], q2 = qrow[sw^2], q3 = qrow[sw^3];
      accA[h] = dot4(q0,kva[0]) + dot4(q1,kva[1]) + dot4(q2,kva[2]) + dot4(q3,kva[3]);
      accB[h] = dot4(q0,kvb[0]) + dot4(q1,kvb[1]) + dot4(q2,kvb[2]) + dot4(q3,kvb[3]);
      if (cs) {
        float4 qr = qr_s[h*17 + cg];
        accA[h] += dot4(qr, kra);
        accB[h] += dot4(qr, krb);
      }
    }
    #pragma unroll
    for (int h = 0; h < 32; ++h) {
      float va = accA[h], vb = accB[h];
      va += __shfl_xor(va, 1); vb += __shfl_xor(vb, 1);
      va += __shfl_xor(va, 2); vb += __shfl_xor(vb, 2);
      va += __shfl_xor(va, 4); vb += __shfl_xor(vb, 4);
      va += __shfl_xor(va, 8); vb += __shfl_xor(vb, 8);
      if (cg == (h & 15)) {
        float* srow = sbuf + (size_t)(b*NH + h)*SKP;
        if (ka <= SS) srow[ka] = va;
        if (kb <= SS) srow[kb] = vb;
      }
    }
  }
}

// ---------------- K5: softmax(SCA+SCB+mask) -> probs in SCA ------------------
__global__ __launch_bounds__(256)
void k_softmax(const float* __restrict__ mask, float* __restrict__ ws) {
  __shared__ float red[256];
  const int tid = threadIdx.x;
  const int b = blockIdx.x >> 5;
  float* sa = ws + WS_SCA + (size_t)blockIdx.x * SKP;
  const float* sb = ws + WS_SCB + (size_t)blockIdx.x * SKP;
  const float* mrow = mask + (size_t)b * SK;
  float v[17];
  float m = -INFINITY;
  #pragma unroll
  for (int r = 0; r < 17; ++r) {
    int k = tid + r*256;
    v[r] = (k < SK) ? (sa[k] + sb[k] + mrow[k] * (-1e9f)) : -INFINITY;
    m = fmaxf(m, v[r]);
  }
  red[tid] = m; __syncthreads();
  for (int st = 128; st > 0; st >>= 1) {
    if (tid < st) red[tid] = fmaxf(red[tid], red[tid+st]);
    __syncthreads();
  }
  m = red[0]; __syncthreads();
  float e[17];
  float l = 0.f;
  #pragma unroll
  for (int r = 0; r < 17; ++r) {
    int k = tid + r*256;
    e[r] = (k < SK) ? __expf(v[r] - m) : 0.f;
    l += e[r];
  }
  red[tid] = l; __syncthreads();
  for (int st = 128; st > 0; st >>= 1) {
    if (tid < st) red[tid] += red[tid+st];
    __syncthreads();
  }
  float inv = 1.f / red[0];
  #pragma unroll
  for (int r = 0; r < 17; ++r) {
    int k = tid + r*256;
    if (k < SK) sa[k] = e[r] * inv;
  }
}

// ---------------- K6: o_latent partials = probs @ c_KV (no atomics) ---------
// grid (NPV, 8, 4); all 32 heads per block; plain float4 stores to OPART.
__global__ __launch_bounds__(256)
void k_pv(const float* __restrict__ kv_cache, float* __restrict__ ws) {
  const int tid = threadIdx.x;
  const int c4 = tid & 15, hg = tid >> 4;      // hg 0..15; heads hg, hg+16
  const int b  = blockIdx.z;
  const int c  = blockIdx.y * 64 + c4 * 4;
  const int k0 = blockIdx.x * (SS / NPV);
  const float* kvp = kv_cache + ((size_t)b*SS + k0)*CKV + c;
  const float* pa = ws + WS_SCA + (size_t)(b*NH + hg)*SKP + k0;
  const float* pb = ws + WS_SCA + (size_t)(b*NH + hg + 16)*SKP + k0;
  float4 acc0 = {}, acc1 = {};
  #pragma unroll 4
  for (int kk = 0; kk < SS / NPV; kk += 4) {
    float4 p4a = *(const float4*)(pa + kk);
    float4 p4b = *(const float4*)(pb + kk);
    float4 kv4[4];
    #pragma unroll
    for (int j = 0; j < 4; ++j)
      kv4[j] = *(const float4*)(kvp + (size_t)(kk + j)*CKV);
    fma4(acc0, p4a.x, kv4[0]); fma4(acc1, p4b.x, kv4[0]);
    fma4(acc0, p4a.y, kv4[1]); fma4(acc1, p4b.y, kv4[1]);
    fma4(acc0, p4a.z, kv4[2]); fma4(acc1, p4b.z, kv4[2]);
    fma4(acc0, p4a.w, kv4[3]); fma4(acc1, p4b.w, kv4[3]);
  }
  if (blockIdx.x == NPV - 1) {  // tail key k == SS
    float4 kv = *(const float4*)(ws + WS_CKV + b*CKV + c);
    fma4(acc0, pa[SS - k0], kv);
    fma4(acc1, pb[SS - k0], kv);
  }
  float* d0 = ws + WS_OPART + (((size_t)blockIdx.x*NB + b)*NH + hg)*CKV + c;
  float* d1 = ws + WS_OPART + (((size_t)blockIdx.x*NB + b)*NH + hg + 16)*CKV + c;
  *(float4*)d0 = acc0;
  *(float4*)d1 = acc1;
}

// ---------------- R3: OLAT = sum_p OPART[p] ----------------------------------
__global__ __launch_bounds__(256)
void k_reduce3(float* __restrict__ ws) {
  const int idx = blockIdx.x * 256 + threadIdx.x;   // < 16384 float4s
  float4 s = {};
  #pragma unroll
  for (int p = 0; p < NPV; ++p) {
    float4 v = *(const float4*)(ws + WS_OPART + (size_t)p*(NB*NH*CKV) + (size_t)idx*4);
    s.x += v.x; s.y += v.y; s.z += v.z; s.w += v.w;
  }
  *(float4*)(ws + WS_OLAT + (size_t)idx*4) = s;
}

// ---------------- K7: UVPART = o_latent @ W_UV (c-chunked, no atomics) ------
__global__ __launch_bounds__(256)
void k_uv(const float* __restrict__ Wuv, float* __restrict__ ws) {
  const int col4 = blockIdx.x * 256 + threadIdx.x;  // < 1024
  const int h = col4 >> 5;
  const int k0 = blockIdx.y * (CKV / NUV);
  const float4* wp = (const float4*)Wuv + (size_t)k0 * 1024 + col4;
  float4 acc[NB] = {};
  #pragma unroll
  for (int i = 0; i < CKV / NUV; ++i) {
    float4 w4 = wp[(size_t)i * 1024];
    #pragma unroll
    for (int b = 0; b < NB; ++b)
      fma4(acc[b], ws[WS_OLAT + (size_t)(b*NH + h)*CKV + k0 + i], w4);
  }
  #pragma unroll
  for (int b = 0; b < NB; ++b)
    *(float4*)(ws + WS_UVPART + (size_t)(blockIdx.y*NB + b)*HID + col4*4) = acc[b];
}

// ---------------- R4: ATTN = sum_p UVPART[p] ---------------------------------
__global__ __launch_bounds__(256)
void k_reduce4(float* __restrict__ ws) {
  const int idx = blockIdx.x * 256 + threadIdx.x;   // < 4096 float4s
  float4 s = {};
  #pragma unroll
  for (int p = 0; p < NUV; ++p) {
    float4 v = *(const float4*)(ws + WS_UVPART + (size_t)p*(NB*HID) + (size_t)idx*4);
    s.x += v.x; s.y += v.y; s.z += v.z; s.w += v.w;
  }
  *(float4*)(ws + WS_ATTN + (size_t)idx*4) = s;
}

// ---------------- K8: WOPART = attn @ W_O (k-chunked, no atomics) ------------
__global__ __launch_bounds__(256)
void k_wo(const float* __restrict__ Wo, const float* __restrict__ ws,
          float* __restrict__ wsp) {
  const int col4 = blockIdx.x * 256 + threadIdx.x;  // < 1024
  const int k0 = blockIdx.y * (HID / NWO);
  const float4* wp = (const float4*)Wo + (size_t)k0 * 1024 + col4;
  float4 acc[NB] = {};
  #pragma unroll 8
  for (int i = 0; i < HID / NWO; ++i) {
    float4 w4 = wp[(size_t)i * 1024];
    #pragma unroll
    for (int b = 0; b < NB; ++b)
      fma4(acc[b], ws[WS_ATTN + b*HID + k0 + i], w4);
  }
  #pragma unroll
  for (int b = 0; b < NB; ++b)
    *(float4*)(wsp + WS_WOPART + (size_t)(blockIdx.y*NB + b)*HID + col4*4) = acc[b];
}

// ---------------- R5: out = sum_p WOPART[p] ----------------------------------
__global__ __launch_bounds__(256)
void k_reduce5(const float* __restrict__ ws, float* __restrict__ out) {
  const int idx = blockIdx.x * 256 + threadIdx.x;   // < 4096 float4s
  float4 s = {};
  #pragma unroll
  for (int p = 0; p < NWO; ++p) {
    float4 v = *(const float4*)(ws + WS_WOPART + (size_t)p*(NB*HID) + (size_t)idx*4);
    s.x += v.x; s.y += v.y; s.z += v.z; s.w += v.w;
  }
  *(float4*)(out + (size_t)idx*4) = s;
}

// ---------------- K9: cache copy (rows 0..4095) ------------------------------
__global__ __launch_bounds__(256)
void k_copy(const float4* __restrict__ src_ckv,
            const float4* __restrict__ src_kr,
            float4* __restrict__ dst_ckv,
            float4* __restrict__ dst_kr) {
  const int bx = blockIdx.x;
  if (bx < 8192) {
    int b = bx >> 11;
    int idx = (bx & 2047) * 256 + threadIdx.x;
    dst_ckv[(size_t)b*(SK*CKV/4) + idx] = src_ckv[(size_t)b*(SS*CKV/4) + idx];
  } else {
    int bx2 = bx - 8192;
    int b = bx2 >> 8;
    int idx = (bx2 & 255) * 256 + threadIdx.x;
    dst_kr[(size_t)b*(SK*RD/4) + idx] = src_kr[(size_t)b*(SS*RD/4) + idx];
  }
}

extern "C" void kernel_launch(void* const* d_in, const int* in_sizes, int n_in,
                              void* d_out, int out_size, void* d_ws, size_t ws_size,
                              hipStream_t stream) {
  (void)in_sizes; (void)n_in; (void)out_size; (void)ws_size;
  const float* hidden = (const float*)d_in[0];
  const float* mask   = (const float*)d_in[1];
  const float* ckv_c  = (const float*)d_in[2];
  const float* kr_c   = (const float*)d_in[3];
  const float* Wdkv   = (const float*)d_in[4];
  const float* Wuk    = (const float*)d_in[5];
  const float* Wuv    = (const float*)d_in[6];
  const float* Wdq    = (const float*)d_in[7];
  const float* Wuq    = (const float*)d_in[8];
  const float* Wqr    = (const float*)d_in[9];
  const float* Wkr    = (const float*)d_in[10];
  const float* Wo     = (const float*)d_in[11];
  float* out = (float*)d_out;
  float* ws  = (float*)d_ws;
  float* out_ckv = out + NB*HID;
  float* out_kr  = out + NB*HID + (size_t)NB*SK*CKV;

  k_copy<<<9216, 256, 0, stream>>>((const float4*)ckv_c, (const float4*)kr_c,
                                   (float4*)out_ckv, (float4*)out_kr);
  k_proj1<<<dim3(3, NP1), 256, 0, stream>>>(hidden, Wdkv, Wdq, Wkr, ws);
  k_reduce1<<<9, 256, 0, stream>>>(ws, out_ckv, out_kr);
  k_proj2<<<dim3(6, NP2), 256, 0, stream>>>(Wuq, Wqr, ws);
  k_absorb_rope<<<260, 256, 0, stream>>>(Wuk, ws);
  k_scores<<<dim3(65, 2, 4), 256, 0, stream>>>(ckv_c, kr_c, ws);
  k_softmax<<<NB*NH, 256, 0, stream>>>(mask, ws);
  k_pv<<<dim3(NPV, 8, 4), 256, 0, stream>>>(ckv_c, ws);
  k_reduce3<<<64, 256, 0, stream>>>(ws);
  k_uv<<<dim3(4, NUV), 256, 0, stream>>>(Wuv, ws);
  k_reduce4<<<16, 256, 0, stream>>>(ws);
  k_wo<<<dim3(4, NWO), 256, 0, stream>>>(Wo, ws, ws);
  k_reduce5<<<16, 256, 0, stream>>>(ws, out);
}

// Round 7
// 156.633 us; speedup vs baseline: 1.6733x; 1.1281x over previous
//
#include <hip/hip_runtime.h>
#include <math.h>

#define NB 4
#define HID 4096
#define CKV 512
#define CQ 1536
#define NH 32
#define HD 128
#define RD 64
#define SS 4096
#define SK 4097
#define SKP 4100  // padded scores row stride

#define SCALE_F 0.07216878364870322f  // 1/sqrt(192)

#define NP1 64   // proj1 k-partials (k-cov 64)
#define NP2 24   // proj2 k-partials (k-cov 64)
#define NPV 32   // pv key-chunks (128 keys)
#define NUV 16   // uv c-partials (c-cov 32)
#define NWO 32   // wo k-partials (k-cov 128)

// workspace offsets (floats). NO memsets — every cell written before read.
// R1 region is lifetime-shared: P1 -> P2 -> OPART -> UVPART -> WOPART
// (each dead before the next producer runs; single stream serializes).
enum : int {
  WS_QABS  = 0,                      // [NB][NH][CKV] pre-scaled
  WS_QROPE = WS_QABS + NB*NH*CKV,    // [NB][NH][RD]  pre-scaled
  WS_KROPE = WS_QROPE + NB*NH*RD,    // [NB][RD]
  WS_CKV   = WS_KROPE + NB*RD,       // [NB][CKV]
  WS_CQ    = WS_CKV + NB*CKV,        // [NB][CQ]
  WS_OLAT  = WS_CQ + NB*CQ,          // [NB][NH][CKV]
  WS_ATTN  = WS_OLAT + NB*NH*CKV,    // [NB][HID]
  WS_SCA   = WS_ATTN + NB*HID,       // [NB][NH][SKP] scores cs=0 -> probs
  WS_SCB   = WS_SCA + NB*NH*SKP,     // [NB][NH][SKP] scores cs=1
  WS_R1    = WS_SCB + NB*NH*SKP,     // 2,097,152 floats (max = OPART)
  WS_TOTAL = WS_R1 + NPV*NB*NH*CKV   // 3,310,848 floats = 13.2 MB
};
#define WS_P1     WS_R1
#define WS_P2     WS_R1
#define WS_OPART  WS_R1
#define WS_UVPART WS_R1
#define WS_WOPART WS_R1

__device__ inline void fma4(float4& a, float s, const float4& v) {
  a.x += s*v.x; a.y += s*v.y; a.z += s*v.z; a.w += s*v.w;
}
__device__ inline float dot4(const float4& a, const float4& b) {
  return a.x*b.x + a.y*b.y + a.z*b.z + a.w*b.w;
}

// ---------------- K1: hidden -> P1 partials (block k-split, LDS reduce) -----
// block: 64 col4-lanes x 4 ksub (k-cov 64). grid (9, 64) = 576 blocks.
__global__ __launch_bounds__(256)
void k_proj1(const float* __restrict__ hidden,
             const float* __restrict__ Wdkv,
             const float* __restrict__ Wdq,
             const float* __restrict__ Wkr,
             float* __restrict__ ws) {
  __shared__ float4 red_s[4][NB][64];
  const int lane = threadIdx.x & 63, ksub = threadIdx.x >> 6;
  const int col4 = blockIdx.x * 64 + lane;
  const int k0 = blockIdx.y * 64 + ksub * 16;
  const bool valid = col4 < 528;
  float4 acc[NB] = {};
  if (valid) {
    const float* W; int C4, wcol4;
    if (col4 < 128)      { W = Wdkv; C4 = 128; wcol4 = col4; }
    else if (col4 < 512) { W = Wdq;  C4 = 384; wcol4 = col4 - 128; }
    else                 { W = Wkr;  C4 = 16;  wcol4 = col4 - 512; }
    const float4* wp = (const float4*)W + (size_t)k0 * C4 + wcol4;
    #pragma unroll
    for (int i = 0; i < 16; ++i) {
      float4 w4 = wp[(size_t)i * C4];
      #pragma unroll
      for (int b = 0; b < NB; ++b) fma4(acc[b], hidden[b*HID + k0 + i], w4);
    }
  }
  #pragma unroll
  for (int b = 0; b < NB; ++b) red_s[ksub][b][lane] = acc[b];
  __syncthreads();
  if (ksub == 0 && valid) {
    #pragma unroll
    for (int b = 0; b < NB; ++b) {
      float4 s = red_s[0][b][lane];
      #pragma unroll
      for (int j = 1; j < 4; ++j) {
        float4 v = red_s[j][b][lane];
        s.x += v.x; s.y += v.y; s.z += v.z; s.w += v.w;
      }
      *(float4*)(ws + WS_P1 + ((size_t)(blockIdx.y*NB + b)*528 + col4)*4) = s;
    }
  }
}

// ---------------- R1: reduce P1 -> c_KV, c_Q; k_R RoPE; new cache rows ------
__global__ __launch_bounds__(256)
void k_reduce1(float* __restrict__ ws,
               float* __restrict__ out_ckv,
               float* __restrict__ out_kr) {
  const int w = blockIdx.x * 256 + threadIdx.x;  // < 2112
  if (w >= 528*NB) return;
  const int b = w / 528, col4 = w % 528;
  float4 s = {};
  #pragma unroll 8
  for (int p = 0; p < NP1; ++p) {
    float4 v = *(const float4*)(ws + WS_P1 + ((size_t)(p*NB + b)*528 + col4)*4);
    s.x += v.x; s.y += v.y; s.z += v.z; s.w += v.w;
  }
  if (col4 < 128) {
    *(float4*)(ws + WS_CKV + b*CKV + col4*4) = s;
    *(float4*)(out_ckv + (size_t)b*SK*CKV + (size_t)SS*CKV + col4*4) = s;
  } else if (col4 < 512) {
    *(float4*)(ws + WS_CQ + b*CQ + (col4 - 128)*4) = s;
  } else {
    const int c0 = (col4 - 512) * 4;
    const double LN1E4 = 9.210340371976184;
    int i0 = c0 >> 1;
    double a0 = 4096.0 * exp(-(double)i0 / 32.0 * LN1E4);
    double a1 = 4096.0 * exp(-(double)(i0 + 1) / 32.0 * LN1E4);
    float c0f = (float)cos(a0), s0f = (float)sin(a0);
    float c1f = (float)cos(a1), s1f = (float)sin(a1);
    float4 o;
    o.x = s.x*c0f - s.y*s0f;  o.y = s.x*s0f + s.y*c0f;
    o.z = s.z*c1f - s.w*s1f;  o.w = s.z*s1f + s.w*c1f;
    *(float4*)(ws + WS_KROPE + b*RD + c0) = o;
    *(float4*)(out_kr + (size_t)b*SK*RD + (size_t)SS*RD + c0) = o;
  }
}

// ---------------- K2: c_Q -> P2 partials (block k-split, LDS reduce) --------
// block: 64 col4-lanes x 4 ksub (k-cov 64). grid (24, 24) = 576 blocks.
__global__ __launch_bounds__(256)
void k_proj2(const float* __restrict__ Wuq,
             const float* __restrict__ Wqr,
             float* __restrict__ ws) {
  __shared__ float4 red_s[4][NB][64];
  const int lane = threadIdx.x & 63, ksub = threadIdx.x >> 6;
  const int col4 = blockIdx.x * 64 + lane;   // < 1536
  const int k0 = blockIdx.y * 64 + ksub * 16;
  const float* W; int C4, wcol4;
  if (col4 < 1024) { W = Wuq; C4 = 1024; wcol4 = col4; }
  else             { W = Wqr; C4 = 512;  wcol4 = col4 - 1024; }
  const float4* wp = (const float4*)W + (size_t)k0 * C4 + wcol4;
  const float* act = ws + WS_CQ;
  float4 acc[NB] = {};
  #pragma unroll
  for (int i = 0; i < 16; ++i) {
    float4 w4 = wp[(size_t)i * C4];
    #pragma unroll
    for (int b = 0; b < NB; ++b) fma4(acc[b], act[b*CQ + k0 + i], w4);
  }
  #pragma unroll
  for (int b = 0; b < NB; ++b) red_s[ksub][b][lane] = acc[b];
  __syncthreads();
  if (ksub == 0) {
    #pragma unroll
    for (int b = 0; b < NB; ++b) {
      float4 s = red_s[0][b][lane];
      #pragma unroll
      for (int j = 1; j < 4; ++j) {
        float4 v = red_s[j][b][lane];
        s.x += v.x; s.y += v.y; s.z += v.z; s.w += v.w;
      }
      *(float4*)(ws + WS_P2 + (size_t)(blockIdx.y*NB + b)*6144 + col4*4) = s;
    }
  }
}

// -------- K3: q_abs = q_C @ W_UK^T (×SCALE), P2-reduce fused; q_R RoPE -------
__global__ __launch_bounds__(256)
void k_absorb_rope(const float* __restrict__ Wuk,
                   float* __restrict__ ws) {
  const int bid = blockIdx.x, tid = threadIdx.x;
  if (bid < 256) {
    const int h = bid >> 3, cq = bid & 7;
    __shared__ float qc_s[NB][HD];
    __shared__ float part_s[NB][256];
    for (int e = tid; e < NB*HD; e += 256) {
      int b = e >> 7, d = e & 127;
      float v = 0.f;
      #pragma unroll
      for (int p = 0; p < NP2; ++p)
        v += ws[WS_P2 + (size_t)(p*NB + b)*6144 + h*HD + d];
      qc_s[b][d] = v;
    }
    __syncthreads();
    const int c = cq*64 + (tid & 63);
    const int dg = tid >> 6;
    const float4* wrow = (const float4*)(Wuk + (size_t)c*(NH*HD) + h*HD + dg*32);
    float acc[NB] = {0,0,0,0};
    #pragma unroll
    for (int d4 = 0; d4 < 8; ++d4) {
      float4 w4 = wrow[d4];
      #pragma unroll
      for (int b = 0; b < NB; ++b)
        acc[b] += dot4(w4, *(const float4*)&qc_s[b][dg*32 + d4*4]);
    }
    #pragma unroll
    for (int b = 0; b < NB; ++b) part_s[b][tid] = acc[b];
    __syncthreads();
    if (tid < 64) {
      #pragma unroll
      for (int b = 0; b < NB; ++b) {
        float v = part_s[b][tid] + part_s[b][tid+64] + part_s[b][tid+128] + part_s[b][tid+192];
        ws[WS_QABS + (size_t)(b*NH + h)*CKV + cq*64 + tid] = v * SCALE_F;
      }
    }
  } else {
    const int b = bid - 256;
    const double LN1E4 = 9.210340371976184;
    for (int pid = tid; pid < NH*32; pid += 256) {
      int h = pid >> 5, i = pid & 31;
      float x1 = 0.f, x2 = 0.f;
      #pragma unroll
      for (int p = 0; p < NP2; ++p) {
        const float* base = ws + WS_P2 + (size_t)(p*NB + b)*6144 + 4096 + h*RD + 2*i;
        x1 += base[0]; x2 += base[1];
      }
      double ang = 4096.0 * exp(-(double)i / 32.0 * LN1E4);
      float cs = (float)cos(ang), sn = (float)sin(ang);
      ws[WS_QROPE + (b*NH + h)*RD + 2*i]     = (x1*cs - x2*sn) * SCALE_F;
      ws[WS_QROPE + (b*NH + h)*RD + 2*i + 1] = (x1*sn + x2*cs) * SCALE_F;
    }
  }
}

// ---------------- K4: scores — LDS-staged q, streamed kv, plain stores ------
__global__ __launch_bounds__(256)
void k_scores(const float* __restrict__ kv_cache,
              const float* __restrict__ kr_cache,
              float* __restrict__ ws) {
  __shared__ float4 q_s[32*65];    // swizzled: slot f stored at f ^ (f>>2)
  __shared__ float4 qr_s[32*17];
  const int tid = threadIdx.x;
  const int b  = blockIdx.z;
  const int cs = blockIdx.y;
  {
    const float4* qabs4 = (const float4*)(ws + WS_QABS) + (size_t)(b*NH)*128;
    for (int e = tid; e < 32*64; e += 256) {
      int h = e >> 6, f = e & 63;
      q_s[h*65 + (f ^ (f >> 2))] = qabs4[h*128 + cs*64 + f];
    }
    if (cs) {
      const float4* qr4 = (const float4*)(ws + WS_QROPE) + (size_t)(b*NH)*16;
      for (int e = tid; e < 32*16; e += 256) {
        int h = e >> 4, s = e & 15;
        qr_s[h*17 + s] = qr4[h*16 + s];
      }
    }
  }
  __syncthreads();
  const int lane = tid & 63, wid = tid >> 6;
  const int cg = lane & 15, kq = lane >> 4;
  const int sw = (cg << 2) ^ cg;
  const int kbase = blockIdx.x * 64 + wid * 16;
  float* sbuf = ws + (cs ? WS_SCB : WS_SCA);

  #pragma unroll
  for (int half = 0; half < 2; ++half) {
    const int ka = kbase + half*8 + kq;
    const int kb = ka + 4;
    const float4* ra =
        (ka < SS)  ? (const float4*)(kv_cache + ((size_t)b*SS + ka)*CKV)
      : (ka == SS) ? (const float4*)(ws + WS_CKV + b*CKV)
                   : (const float4*)(ws + WS_CKV);
    const float4* rb =
        (kb < SS)  ? (const float4*)(kv_cache + ((size_t)b*SS + kb)*CKV)
      : (kb == SS) ? (const float4*)(ws + WS_CKV + b*CKV)
                   : (const float4*)(ws + WS_CKV);
    float4 kva[4], kvb[4];
    #pragma unroll
    for (int j = 0; j < 4; ++j) {
      kva[j] = ra[cs*64 + cg*4 + j];
      kvb[j] = rb[cs*64 + cg*4 + j];
    }
    float4 kra = make_float4(0,0,0,0), krb = make_float4(0,0,0,0);
    if (cs) {
      const float4* rra =
          (ka < SS)  ? (const float4*)(kr_cache + ((size_t)b*SS + ka)*RD)
        : (ka == SS) ? (const float4*)(ws + WS_KROPE + b*RD)
                     : (const float4*)(ws + WS_KROPE);
      const float4* rrb =
          (kb < SS)  ? (const float4*)(kr_cache + ((size_t)b*SS + kb)*RD)
        : (kb == SS) ? (const float4*)(ws + WS_KROPE + b*RD)
                     : (const float4*)(ws + WS_KROPE);
      kra = rra[cg];
      krb = rrb[cg];
    }
    float accA[32], accB[32];
    #pragma unroll
    for (int h = 0; h < 32; ++h) {
      const float4* qrow = &q_s[h*65];
      float4 q0 = qrow[sw], q1 = qrow[sw^1], q2 = qrow[sw^2], q3 = qrow[sw^3];
      accA[h] = dot4(q0,kva[0]) + dot4(q1,kva[1]) + dot4(q2,kva[2]) + dot4(q3,kva[3]);
      accB[h] = dot4(q0,kvb[0]) + dot4(q1,kvb[1]) + dot4(q2,kvb[2]) + dot4(q3,kvb[3]);
      if (cs) {
        float4 qr = qr_s[h*17 + cg];
        accA[h] += dot4(qr, kra);
        accB[h] += dot4(qr, krb);
      }
    }
    #pragma unroll
    for (int h = 0; h < 32; ++h) {
      float va = accA[h], vb = accB[h];
      va += __shfl_xor(va, 1); vb += __shfl_xor(vb, 1);
      va += __shfl_xor(va, 2); vb += __shfl_xor(vb, 2);
      va += __shfl_xor(va, 4); vb += __shfl_xor(vb, 4);
      va += __shfl_xor(va, 8); vb += __shfl_xor(vb, 8);
      if (cg == (h & 15)) {
        float* srow = sbuf + (size_t)(b*NH + h)*SKP;
        if (ka <= SS) srow[ka] = va;
        if (kb <= SS) srow[kb] = vb;
      }
    }
  }
}

// ---------------- K5: softmax(SCA+SCB+mask) -> probs in SCA ------------------
__global__ __launch_bounds__(256)
void k_softmax(const float* __restrict__ mask, float* __restrict__ ws) {
  __shared__ float red[256];
  const int tid = threadIdx.x;
  const int b = blockIdx.x >> 5;
  float* sa = ws + WS_SCA + (size_t)blockIdx.x * SKP;
  const float* sb = ws + WS_SCB + (size_t)blockIdx.x * SKP;
  const float* mrow = mask + (size_t)b * SK;
  float v[17];
  float m = -INFINITY;
  #pragma unroll
  for (int r = 0; r < 17; ++r) {
    int k = tid + r*256;
    v[r] = (k < SK) ? (sa[k] + sb[k] + mrow[k] * (-1e9f)) : -INFINITY;
    m = fmaxf(m, v[r]);
  }
  red[tid] = m; __syncthreads();
  for (int st = 128; st > 0; st >>= 1) {
    if (tid < st) red[tid] = fmaxf(red[tid], red[tid+st]);
    __syncthreads();
  }
  m = red[0]; __syncthreads();
  float e[17];
  float l = 0.f;
  #pragma unroll
  for (int r = 0; r < 17; ++r) {
    int k = tid + r*256;
    e[r] = (k < SK) ? __expf(v[r] - m) : 0.f;
    l += e[r];
  }
  red[tid] = l; __syncthreads();
  for (int st = 128; st > 0; st >>= 1) {
    if (tid < st) red[tid] += red[tid+st];
    __syncthreads();
  }
  float inv = 1.f / red[0];
  #pragma unroll
  for (int r = 0; r < 17; ++r) {
    int k = tid + r*256;
    if (k < SK) sa[k] = e[r] * inv;
  }
}

// ---------------- K6: o_latent partials — LDS-staged probs ------------------
// grid (NPV=32, 8, 4) = 1024 blocks; 128-key chunk; probs in LDS (padded).
__global__ __launch_bounds__(256)
void k_pv(const float* __restrict__ kv_cache, float* __restrict__ ws) {
  __shared__ float p_s[32][132];   // +4 pad: head-rows start in distinct banks
  const int tid = threadIdx.x;
  const int c4 = tid & 15, hg = tid >> 4;      // heads hg, hg+16
  const int b  = blockIdx.z;
  const int c  = blockIdx.y * 64 + c4 * 4;
  const int k0 = blockIdx.x * 128;
  // stage probs: 32 heads x 128 keys, coalesced float4
  #pragma unroll
  for (int j = 0; j < 4; ++j) {
    int e = tid + j*256;                       // 0..1023
    int h = e >> 5, k4 = e & 31;
    *(float4*)&p_s[h][k4*4] =
        *(const float4*)(ws + WS_SCA + (size_t)(b*NH + h)*SKP + k0 + k4*4);
  }
  __syncthreads();
  const float* kvp = kv_cache + ((size_t)b*SS + k0)*CKV + c;
  float4 acc0 = {}, acc1 = {};
  #pragma unroll 4
  for (int kk = 0; kk < 128; kk += 4) {
    float4 kv4[4];
    #pragma unroll
    for (int j = 0; j < 4; ++j)
      kv4[j] = *(const float4*)(kvp + (size_t)(kk + j)*CKV);
    float4 p4a = *(const float4*)&p_s[hg][kk];
    float4 p4b = *(const float4*)&p_s[hg + 16][kk];
    fma4(acc0, p4a.x, kv4[0]); fma4(acc1, p4b.x, kv4[0]);
    fma4(acc0, p4a.y, kv4[1]); fma4(acc1, p4b.y, kv4[1]);
    fma4(acc0, p4a.z, kv4[2]); fma4(acc1, p4b.z, kv4[2]);
    fma4(acc0, p4a.w, kv4[3]); fma4(acc1, p4b.w, kv4[3]);
  }
  if (blockIdx.x == NPV - 1) {   // tail key k == SS (not staged)
    float4 kv = *(const float4*)(ws + WS_CKV + b*CKV + c);
    float pa = ws[WS_SCA + (size_t)(b*NH + hg)*SKP + SS];
    float pb = ws[WS_SCA + (size_t)(b*NH + hg + 16)*SKP + SS];
    fma4(acc0, pa, kv);
    fma4(acc1, pb, kv);
  }
  *(float4*)(ws + WS_OPART + (((size_t)blockIdx.x*NB + b)*NH + hg)*CKV + c) = acc0;
  *(float4*)(ws + WS_OPART + (((size_t)blockIdx.x*NB + b)*NH + hg + 16)*CKV + c) = acc1;
}

// ---------------- R3: OLAT = sum_p OPART[p] ----------------------------------
__global__ __launch_bounds__(256)
void k_reduce3(float* __restrict__ ws) {
  const int idx = blockIdx.x * 256 + threadIdx.x;   // < 16384 float4s
  float4 s = {};
  #pragma unroll 8
  for (int p = 0; p < NPV; ++p) {
    float4 v = *(const float4*)(ws + WS_OPART + (size_t)p*(NB*NH*CKV) + (size_t)idx*4);
    s.x += v.x; s.y += v.y; s.z += v.z; s.w += v.w;
  }
  *(float4*)(ws + WS_OLAT + (size_t)idx*4) = s;
}

// ---------------- K7: UVPART = o_latent @ W_UV (block c-split) --------------
// block: 64 col4-lanes x 4 csub (c-cov 32). grid (16, 16) = 256 blocks.
__global__ __launch_bounds__(256)
void k_uv(const float* __restrict__ Wuv, float* __restrict__ ws) {
  __shared__ float4 red_s[4][NB][64];
  const int lane = threadIdx.x & 63, csub = threadIdx.x >> 6;
  const int col4 = blockIdx.x * 64 + lane;   // < 1024
  const int h = col4 >> 5;
  const int k0 = blockIdx.y * 32 + csub * 8;
  const float4* wp = (const float4*)Wuv + (size_t)k0 * 1024 + col4;
  float4 acc[NB] = {};
  #pragma unroll
  for (int i = 0; i < 8; ++i) {
    float4 w4 = wp[(size_t)i * 1024];
    #pragma unroll
    for (int b = 0; b < NB; ++b)
      fma4(acc[b], ws[WS_OLAT + (size_t)(b*NH + h)*CKV + k0 + i], w4);
  }
  #pragma unroll
  for (int b = 0; b < NB; ++b) red_s[csub][b][lane] = acc[b];
  __syncthreads();
  if (csub == 0) {
    #pragma unroll
    for (int b = 0; b < NB; ++b) {
      float4 s = red_s[0][b][lane];
      #pragma unroll
      for (int j = 1; j < 4; ++j) {
        float4 v = red_s[j][b][lane];
        s.x += v.x; s.y += v.y; s.z += v.z; s.w += v.w;
      }
      *(float4*)(ws + WS_UVPART + (size_t)(blockIdx.y*NB + b)*HID + col4*4) = s;
    }
  }
}

// ---------------- R4: ATTN = sum_p UVPART[p] ---------------------------------
__global__ __launch_bounds__(256)
void k_reduce4(float* __restrict__ ws) {
  const int idx = blockIdx.x * 256 + threadIdx.x;   // < 4096 float4s
  float4 s = {};
  #pragma unroll
  for (int p = 0; p < NUV; ++p) {
    float4 v = *(const float4*)(ws + WS_UVPART + (size_t)p*(NB*HID) + (size_t)idx*4);
    s.x += v.x; s.y += v.y; s.z += v.z; s.w += v.w;
  }
  *(float4*)(ws + WS_ATTN + (size_t)idx*4) = s;
}

// ---------------- K8: WOPART = attn @ W_O (block k-split) --------------------
// block: 64 col4-lanes x 4 ksub (k-cov 128). grid (16, 32) = 512 blocks.
__global__ __launch_bounds__(256)
void k_wo(const float* __restrict__ Wo, const float* __restrict__ ws,
          float* __restrict__ wsp) {
  __shared__ float4 red_s[4][NB][64];
  const int lane = threadIdx.x & 63, ksub = threadIdx.x >> 6;
  const int col4 = blockIdx.x * 64 + lane;   // < 1024
  const int k0 = blockIdx.y * 128 + ksub * 32;
  const float4* wp = (const float4*)Wo + (size_t)k0 * 1024 + col4;
  float4 acc[NB] = {};
  #pragma unroll 8
  for (int i = 0; i < 32; ++i) {
    float4 w4 = wp[(size_t)i * 1024];
    #pragma unroll
    for (int b = 0; b < NB; ++b)
      fma4(acc[b], ws[WS_ATTN + b*HID + k0 + i], w4);
  }
  #pragma unroll
  for (int b = 0; b < NB; ++b) red_s[ksub][b][lane] = acc[b];
  __syncthreads();
  if (ksub == 0) {
    #pragma unroll
    for (int b = 0; b < NB; ++b) {
      float4 s = red_s[0][b][lane];
      #pragma unroll
      for (int j = 1; j < 4; ++j) {
        float4 v = red_s[j][b][lane];
        s.x += v.x; s.y += v.y; s.z += v.z; s.w += v.w;
      }
      *(float4*)(wsp + WS_WOPART + (size_t)(blockIdx.y*NB + b)*HID + col4*4) = s;
    }
  }
}

// ---------------- R5: out = sum_p WOPART[p] ----------------------------------
__global__ __launch_bounds__(256)
void k_reduce5(const float* __restrict__ ws, float* __restrict__ out) {
  const int idx = blockIdx.x * 256 + threadIdx.x;   // < 4096 float4s
  float4 s = {};
  #pragma unroll 8
  for (int p = 0; p < NWO; ++p) {
    float4 v = *(const float4*)(ws + WS_WOPART + (size_t)p*(NB*HID) + (size_t)idx*4);
    s.x += v.x; s.y += v.y; s.z += v.z; s.w += v.w;
  }
  *(float4*)(out + (size_t)idx*4) = s;
}

// ---------------- K9: cache copy (rows 0..4095) ------------------------------
__global__ __launch_bounds__(256)
void k_copy(const float4* __restrict__ src_ckv,
            const float4* __restrict__ src_kr,
            float4* __restrict__ dst_ckv,
            float4* __restrict__ dst_kr) {
  const int bx = blockIdx.x;
  if (bx < 8192) {
    int b = bx >> 11;
    int idx = (bx & 2047) * 256 + threadIdx.x;
    dst_ckv[(size_t)b*(SK*CKV/4) + idx] = src_ckv[(size_t)b*(SS*CKV/4) + idx];
  } else {
    int bx2 = bx - 8192;
    int b = bx2 >> 8;
    int idx = (bx2 & 255) * 256 + threadIdx.x;
    dst_kr[(size_t)b*(SK*RD/4) + idx] = src_kr[(size_t)b*(SS*RD/4) + idx];
  }
}

extern "C" void kernel_launch(void* const* d_in, const int* in_sizes, int n_in,
                              void* d_out, int out_size, void* d_ws, size_t ws_size,
                              hipStream_t stream) {
  (void)in_sizes; (void)n_in; (void)out_size; (void)ws_size;
  const float* hidden = (const float*)d_in[0];
  const float* mask   = (const float*)d_in[1];
  const float* ckv_c  = (const float*)d_in[2];
  const float* kr_c   = (const float*)d_in[3];
  const float* Wdkv   = (const float*)d_in[4];
  const float* Wuk    = (const float*)d_in[5];
  const float* Wuv    = (const float*)d_in[6];
  const float* Wdq    = (const float*)d_in[7];
  const float* Wuq    = (const float*)d_in[8];
  const float* Wqr    = (const float*)d_in[9];
  const float* Wkr    = (const float*)d_in[10];
  const float* Wo     = (const float*)d_in[11];
  float* out = (float*)d_out;
  float* ws  = (float*)d_ws;
  float* out_ckv = out + NB*HID;
  float* out_kr  = out + NB*HID + (size_t)NB*SK*CKV;

  k_copy<<<9216, 256, 0, stream>>>((const float4*)ckv_c, (const float4*)kr_c,
                                   (float4*)out_ckv, (float4*)out_kr);
  k_proj1<<<dim3(9, NP1), 256, 0, stream>>>(hidden, Wdkv, Wdq, Wkr, ws);
  k_reduce1<<<9, 256, 0, stream>>>(ws, out_ckv, out_kr);
  k_proj2<<<dim3(24, NP2), 256, 0, stream>>>(Wuq, Wqr, ws);
  k_absorb_rope<<<260, 256, 0, stream>>>(Wuk, ws);
  k_scores<<<dim3(65, 2, 4), 256, 0, stream>>>(ckv_c, kr_c, ws);
  k_softmax<<<NB*NH, 256, 0, stream>>>(mask, ws);
  k_pv<<<dim3(NPV, 8, 4), 256, 0, stream>>>(ckv_c, ws);
  k_reduce3<<<64, 256, 0, stream>>>(ws);
  k_uv<<<dim3(16, NUV), 256, 0, stream>>>(Wuv, ws);
  k_reduce4<<<16, 256, 0, stream>>>(ws);
  k_wo<<<dim3(16, NWO), 256, 0, stream>>>(Wo, ws, ws);
  k_reduce5<<<16, 256, 0, stream>>>(ws, out);
}

// Round 8
// 155.841 us; speedup vs baseline: 1.6818x; 1.0051x over previous
//
#include <hip/hip_runtime.h>
#include <math.h>

#define NB 4
#define HID 4096
#define CKV 512
#define CQ 1536
#define NH 32
#define HD 128
#define RD 64
#define SS 4096
#define SK 4097
#define SKP 4100  // padded scores row stride

#define SCALE_F 0.07216878364870322f  // 1/sqrt(192)

#define NP1 64   // proj1 k-partials (k-cov 64)
#define NP2 24   // proj2 k-partials (k-cov 64)
#define NPV 32   // pv key-chunks (128 keys)
#define NUV 16   // uv c-partials (c-cov 32)
#define NWO 32   // wo k-partials (k-cov 128)

// workspace offsets (floats). NO memsets — every cell written before read.
// R1 region is lifetime-shared: P1 -> P2 -> OPART -> UVPART -> WOPART.
enum : int {
  WS_QABS  = 0,                      // [NB][NH][CKV] pre-scaled
  WS_QROPE = WS_QABS + NB*NH*CKV,    // [NB][NH][RD]  pre-scaled
  WS_KROPE = WS_QROPE + NB*NH*RD,    // [NB][RD]
  WS_CKV   = WS_KROPE + NB*RD,       // [NB][CKV]
  WS_CQ    = WS_CKV + NB*CKV,        // [NB][CQ]
  WS_OLAT  = WS_CQ + NB*CQ,          // [NB][NH][CKV]
  WS_ATTN  = WS_OLAT + NB*NH*CKV,    // [NB][HID]
  WS_SCA   = WS_ATTN + NB*HID,       // [NB][NH][SKP] scores cs=0 -> probs
  WS_SCB   = WS_SCA + NB*NH*SKP,     // [NB][NH][SKP] scores cs=1
  WS_R1    = WS_SCB + NB*NH*SKP,     // 2,097,152 floats (max = OPART)
  WS_TOTAL = WS_R1 + NPV*NB*NH*CKV
};
#define WS_P1     WS_R1
#define WS_P2     WS_R1
#define WS_OPART  WS_R1
#define WS_UVPART WS_R1
#define WS_WOPART WS_R1

__device__ inline void fma4(float4& a, float s, const float4& v) {
  a.x += s*v.x; a.y += s*v.y; a.z += s*v.z; a.w += s*v.w;
}
__device__ inline float dot4(const float4& a, const float4& b) {
  return a.x*b.x + a.y*b.y + a.z*b.z + a.w*b.w;
}

// ---------------- K1: hidden -> P1 partials (block k-split, LDS reduce) -----
__global__ __launch_bounds__(256)
void k_proj1(const float* __restrict__ hidden,
             const float* __restrict__ Wdkv,
             const float* __restrict__ Wdq,
             const float* __restrict__ Wkr,
             float* __restrict__ ws) {
  __shared__ float4 red_s[4][NB][64];
  const int lane = threadIdx.x & 63, ksub = threadIdx.x >> 6;
  const int col4 = blockIdx.x * 64 + lane;
  const int k0 = blockIdx.y * 64 + ksub * 16;
  const bool valid = col4 < 528;
  float4 acc[NB] = {};
  if (valid) {
    const float* W; int C4, wcol4;
    if (col4 < 128)      { W = Wdkv; C4 = 128; wcol4 = col4; }
    else if (col4 < 512) { W = Wdq;  C4 = 384; wcol4 = col4 - 128; }
    else                 { W = Wkr;  C4 = 16;  wcol4 = col4 - 512; }
    const float4* wp = (const float4*)W + (size_t)k0 * C4 + wcol4;
    #pragma unroll
    for (int i = 0; i < 16; ++i) {
      float4 w4 = wp[(size_t)i * C4];
      #pragma unroll
      for (int b = 0; b < NB; ++b) fma4(acc[b], hidden[b*HID + k0 + i], w4);
    }
  }
  #pragma unroll
  for (int b = 0; b < NB; ++b) red_s[ksub][b][lane] = acc[b];
  __syncthreads();
  if (ksub == 0 && valid) {
    #pragma unroll
    for (int b = 0; b < NB; ++b) {
      float4 s = red_s[0][b][lane];
      #pragma unroll
      for (int j = 1; j < 4; ++j) {
        float4 v = red_s[j][b][lane];
        s.x += v.x; s.y += v.y; s.z += v.z; s.w += v.w;
      }
      *(float4*)(ws + WS_P1 + ((size_t)(blockIdx.y*NB + b)*528 + col4)*4) = s;
    }
  }
}

// ---------------- R1: reduce P1 -> c_KV, c_Q; k_R RoPE; new cache rows ------
__global__ __launch_bounds__(256)
void k_reduce1(float* __restrict__ ws,
               float* __restrict__ out_ckv,
               float* __restrict__ out_kr) {
  const int w = blockIdx.x * 256 + threadIdx.x;  // < 2112
  if (w >= 528*NB) return;
  const int b = w / 528, col4 = w % 528;
  float4 s = {};
  #pragma unroll 8
  for (int p = 0; p < NP1; ++p) {
    float4 v = *(const float4*)(ws + WS_P1 + ((size_t)(p*NB + b)*528 + col4)*4);
    s.x += v.x; s.y += v.y; s.z += v.z; s.w += v.w;
  }
  if (col4 < 128) {
    *(float4*)(ws + WS_CKV + b*CKV + col4*4) = s;
    *(float4*)(out_ckv + (size_t)b*SK*CKV + (size_t)SS*CKV + col4*4) = s;
  } else if (col4 < 512) {
    *(float4*)(ws + WS_CQ + b*CQ + (col4 - 128)*4) = s;
  } else {
    const int c0 = (col4 - 512) * 4;
    const double LN1E4 = 9.210340371976184;
    int i0 = c0 >> 1;
    double a0 = 4096.0 * exp(-(double)i0 / 32.0 * LN1E4);
    double a1 = 4096.0 * exp(-(double)(i0 + 1) / 32.0 * LN1E4);
    float c0f = (float)cos(a0), s0f = (float)sin(a0);
    float c1f = (float)cos(a1), s1f = (float)sin(a1);
    float4 o;
    o.x = s.x*c0f - s.y*s0f;  o.y = s.x*s0f + s.y*c0f;
    o.z = s.z*c1f - s.w*s1f;  o.w = s.z*s1f + s.w*c1f;
    *(float4*)(ws + WS_KROPE + b*RD + c0) = o;
    *(float4*)(out_kr + (size_t)b*SK*RD + (size_t)SS*RD + c0) = o;
  }
}

// ---------------- K2: c_Q -> P2 partials (block k-split, LDS reduce) --------
__global__ __launch_bounds__(256)
void k_proj2(const float* __restrict__ Wuq,
             const float* __restrict__ Wqr,
             float* __restrict__ ws) {
  __shared__ float4 red_s[4][NB][64];
  const int lane = threadIdx.x & 63, ksub = threadIdx.x >> 6;
  const int col4 = blockIdx.x * 64 + lane;   // < 1536
  const int k0 = blockIdx.y * 64 + ksub * 16;
  const float* W; int C4, wcol4;
  if (col4 < 1024) { W = Wuq; C4 = 1024; wcol4 = col4; }
  else             { W = Wqr; C4 = 512;  wcol4 = col4 - 1024; }
  const float4* wp = (const float4*)W + (size_t)k0 * C4 + wcol4;
  const float* act = ws + WS_CQ;
  float4 acc[NB] = {};
  #pragma unroll
  for (int i = 0; i < 16; ++i) {
    float4 w4 = wp[(size_t)i * C4];
    #pragma unroll
    for (int b = 0; b < NB; ++b) fma4(acc[b], act[b*CQ + k0 + i], w4);
  }
  #pragma unroll
  for (int b = 0; b < NB; ++b) red_s[ksub][b][lane] = acc[b];
  __syncthreads();
  if (ksub == 0) {
    #pragma unroll
    for (int b = 0; b < NB; ++b) {
      float4 s = red_s[0][b][lane];
      #pragma unroll
      for (int j = 1; j < 4; ++j) {
        float4 v = red_s[j][b][lane];
        s.x += v.x; s.y += v.y; s.z += v.z; s.w += v.w;
      }
      *(float4*)(ws + WS_P2 + (size_t)(blockIdx.y*NB + b)*6144 + col4*4) = s;
    }
  }
}

// -------- K3: q_abs = q_C @ W_UK^T (×SCALE), P2-reduce fused; q_R RoPE -------
__global__ __launch_bounds__(256)
void k_absorb_rope(const float* __restrict__ Wuk,
                   float* __restrict__ ws) {
  const int bid = blockIdx.x, tid = threadIdx.x;
  if (bid < 256) {
    const int h = bid >> 3, cq = bid & 7;
    __shared__ float qc_s[NB][HD];
    __shared__ float part_s[NB][256];
    for (int e = tid; e < NB*HD; e += 256) {
      int b = e >> 7, d = e & 127;
      float v = 0.f;
      #pragma unroll
      for (int p = 0; p < NP2; ++p)
        v += ws[WS_P2 + (size_t)(p*NB + b)*6144 + h*HD + d];
      qc_s[b][d] = v;
    }
    __syncthreads();
    const int c = cq*64 + (tid & 63);
    const int dg = tid >> 6;
    const float4* wrow = (const float4*)(Wuk + (size_t)c*(NH*HD) + h*HD + dg*32);
    float acc[NB] = {0,0,0,0};
    #pragma unroll
    for (int d4 = 0; d4 < 8; ++d4) {
      float4 w4 = wrow[d4];
      #pragma unroll
      for (int b = 0; b < NB; ++b)
        acc[b] += dot4(w4, *(const float4*)&qc_s[b][dg*32 + d4*4]);
    }
    #pragma unroll
    for (int b = 0; b < NB; ++b) part_s[b][tid] = acc[b];
    __syncthreads();
    if (tid < 64) {
      #pragma unroll
      for (int b = 0; b < NB; ++b) {
        float v = part_s[b][tid] + part_s[b][tid+64] + part_s[b][tid+128] + part_s[b][tid+192];
        ws[WS_QABS + (size_t)(b*NH + h)*CKV + cq*64 + tid] = v * SCALE_F;
      }
    }
  } else {
    const int b = bid - 256;
    const double LN1E4 = 9.210340371976184;
    for (int pid = tid; pid < NH*32; pid += 256) {
      int h = pid >> 5, i = pid & 31;
      float x1 = 0.f, x2 = 0.f;
      #pragma unroll
      for (int p = 0; p < NP2; ++p) {
        const float* base = ws + WS_P2 + (size_t)(p*NB + b)*6144 + 4096 + h*RD + 2*i;
        x1 += base[0]; x2 += base[1];
      }
      double ang = 4096.0 * exp(-(double)i / 32.0 * LN1E4);
      float cs = (float)cos(ang), sn = (float)sin(ang);
      ws[WS_QROPE + (b*NH + h)*RD + 2*i]     = (x1*cs - x2*sn) * SCALE_F;
      ws[WS_QROPE + (b*NH + h)*RD + 2*i + 1] = (x1*sn + x2*cs) * SCALE_F;
    }
  }
}

// ---------------- K4: scores v3 — 32-key blocks, 40KB LDS, merged h-loop ----
// grid (129, 2, 4) = 1032 blocks (4 blocks/CU). Wave: 8 keys (kq + kq+4).
// kv/kr loads issued BEFORE the staging barrier (latency overlap).
__global__ __launch_bounds__(256)
void k_scores(const float* __restrict__ kv_cache,
              const float* __restrict__ kr_cache,
              float* __restrict__ ws) {
  __shared__ float4 q_s[32*64];    // 32 KB; slot f stored at f ^ (f>>2)
  __shared__ float4 qr_s[32*16];   // 8 KB
  const int tid = threadIdx.x;
  const int b  = blockIdx.z;
  const int cs = blockIdx.y;
  const int lane = tid & 63, wid = tid >> 6;
  const int cg = lane & 15, kq = lane >> 4;
  const int kbase = blockIdx.x * 32 + wid * 8;
  const int ka = kbase + kq;
  const int kb = ka + 4;

  // ---- issue global kv/kr loads first (overlap with q staging + barrier)
  const float4* ra =
      (ka < SS)  ? (const float4*)(kv_cache + ((size_t)b*SS + ka)*CKV)
    : (ka == SS) ? (const float4*)(ws + WS_CKV + b*CKV)
                 : (const float4*)(ws + WS_CKV);
  const float4* rb =
      (kb < SS)  ? (const float4*)(kv_cache + ((size_t)b*SS + kb)*CKV)
    : (kb == SS) ? (const float4*)(ws + WS_CKV + b*CKV)
                 : (const float4*)(ws + WS_CKV);
  float4 kva[4], kvb[4];
  #pragma unroll
  for (int j = 0; j < 4; ++j) {
    kva[j] = ra[cs*64 + cg*4 + j];
    kvb[j] = rb[cs*64 + cg*4 + j];
  }
  float4 kra = make_float4(0,0,0,0), krb = make_float4(0,0,0,0);
  if (cs) {
    const float4* rra =
        (ka < SS)  ? (const float4*)(kr_cache + ((size_t)b*SS + ka)*RD)
      : (ka == SS) ? (const float4*)(ws + WS_KROPE + b*RD)
                   : (const float4*)(ws + WS_KROPE);
    const float4* rrb =
        (kb < SS)  ? (const float4*)(kr_cache + ((size_t)b*SS + kb)*RD)
      : (kb == SS) ? (const float4*)(ws + WS_KROPE + b*RD)
                   : (const float4*)(ws + WS_KROPE);
    kra = rra[cg];
    krb = rrb[cg];
  }

  // ---- stage q (coalesced), 6-bit XOR swizzle
  {
    const float4* qabs4 = (const float4*)(ws + WS_QABS) + (size_t)(b*NH)*128;
    for (int e = tid; e < 32*64; e += 256) {
      int h = e >> 6, f = e & 63;
      q_s[h*64 + (f ^ (f >> 2))] = qabs4[h*128 + cs*64 + f];
    }
    if (cs) {
      const float4* qr4 = (const float4*)(ws + WS_QROPE) + (size_t)(b*NH)*16;
      for (int e = tid; e < 32*16; e += 256) qr_s[e] = qr4[e];
    }
  }
  __syncthreads();

  const int sw = (cg << 2) ^ cg;
  float* sbuf = ws + (cs ? WS_SCB : WS_SCA);
  #pragma unroll 4
  for (int h = 0; h < 32; ++h) {
    const float4* qrow = &q_s[h*64];
    float4 q0 = qrow[sw], q1 = qrow[sw^1], q2 = qrow[sw^2], q3 = qrow[sw^3];
    float va = dot4(q0,kva[0]) + dot4(q1,kva[1]) + dot4(q2,kva[2]) + dot4(q3,kva[3]);
    float vb = dot4(q0,kvb[0]) + dot4(q1,kvb[1]) + dot4(q2,kvb[2]) + dot4(q3,kvb[3]);
    if (cs) {
      float4 qr = qr_s[h*16 + cg];
      va += dot4(qr, kra);
      vb += dot4(qr, krb);
    }
    va += __shfl_xor(va, 1); vb += __shfl_xor(vb, 1);
    va += __shfl_xor(va, 2); vb += __shfl_xor(vb, 2);
    va += __shfl_xor(va, 4); vb += __shfl_xor(vb, 4);
    va += __shfl_xor(va, 8); vb += __shfl_xor(vb, 8);
    if (cg == (h & 15)) {
      float* srow = sbuf + (size_t)(b*NH + h)*SKP;
      if (ka <= SS) srow[ka] = va;
      if (kb <= SS) srow[kb] = vb;
    }
  }
}

// ---------------- K5: softmax(SCA+SCB+mask) -> probs in SCA ------------------
__global__ __launch_bounds__(256)
void k_softmax(const float* __restrict__ mask, float* __restrict__ ws) {
  __shared__ float red[256];
  const int tid = threadIdx.x;
  const int b = blockIdx.x >> 5;
  float* sa = ws + WS_SCA + (size_t)blockIdx.x * SKP;
  const float* sb = ws + WS_SCB + (size_t)blockIdx.x * SKP;
  const float* mrow = mask + (size_t)b * SK;
  float v[17];
  float m = -INFINITY;
  #pragma unroll
  for (int r = 0; r < 17; ++r) {
    int k = tid + r*256;
    v[r] = (k < SK) ? (sa[k] + sb[k] + mrow[k] * (-1e9f)) : -INFINITY;
    m = fmaxf(m, v[r]);
  }
  red[tid] = m; __syncthreads();
  for (int st = 128; st > 0; st >>= 1) {
    if (tid < st) red[tid] = fmaxf(red[tid], red[tid+st]);
    __syncthreads();
  }
  m = red[0]; __syncthreads();
  float e[17];
  float l = 0.f;
  #pragma unroll
  for (int r = 0; r < 17; ++r) {
    int k = tid + r*256;
    e[r] = (k < SK) ? __expf(v[r] - m) : 0.f;
    l += e[r];
  }
  red[tid] = l; __syncthreads();
  for (int st = 128; st > 0; st >>= 1) {
    if (tid < st) red[tid] += red[tid+st];
    __syncthreads();
  }
  float inv = 1.f / red[0];
  #pragma unroll
  for (int r = 0; r < 17; ++r) {
    int k = tid + r*256;
    if (k < SK) sa[k] = e[r] * inv;
  }
}

// ---------------- K6: o_latent partials — LDS-staged probs ------------------
__global__ __launch_bounds__(256)
void k_pv(const float* __restrict__ kv_cache, float* __restrict__ ws) {
  __shared__ float p_s[32][132];
  const int tid = threadIdx.x;
  const int c4 = tid & 15, hg = tid >> 4;
  const int b  = blockIdx.z;
  const int c  = blockIdx.y * 64 + c4 * 4;
  const int k0 = blockIdx.x * 128;
  #pragma unroll
  for (int j = 0; j < 4; ++j) {
    int e = tid + j*256;
    int h = e >> 5, k4 = e & 31;
    *(float4*)&p_s[h][k4*4] =
        *(const float4*)(ws + WS_SCA + (size_t)(b*NH + h)*SKP + k0 + k4*4);
  }
  __syncthreads();
  const float* kvp = kv_cache + ((size_t)b*SS + k0)*CKV + c;
  float4 acc0 = {}, acc1 = {};
  #pragma unroll 4
  for (int kk = 0; kk < 128; kk += 4) {
    float4 kv4[4];
    #pragma unroll
    for (int j = 0; j < 4; ++j)
      kv4[j] = *(const float4*)(kvp + (size_t)(kk + j)*CKV);
    float4 p4a = *(const float4*)&p_s[hg][kk];
    float4 p4b = *(const float4*)&p_s[hg + 16][kk];
    fma4(acc0, p4a.x, kv4[0]); fma4(acc1, p4b.x, kv4[0]);
    fma4(acc0, p4a.y, kv4[1]); fma4(acc1, p4b.y, kv4[1]);
    fma4(acc0, p4a.z, kv4[2]); fma4(acc1, p4b.z, kv4[2]);
    fma4(acc0, p4a.w, kv4[3]); fma4(acc1, p4b.w, kv4[3]);
  }
  if (blockIdx.x == NPV - 1) {
    float4 kv = *(const float4*)(ws + WS_CKV + b*CKV + c);
    float pa = ws[WS_SCA + (size_t)(b*NH + hg)*SKP + SS];
    float pb = ws[WS_SCA + (size_t)(b*NH + hg + 16)*SKP + SS];
    fma4(acc0, pa, kv);
    fma4(acc1, pb, kv);
  }
  *(float4*)(ws + WS_OPART + (((size_t)blockIdx.x*NB + b)*NH + hg)*CKV + c) = acc0;
  *(float4*)(ws + WS_OPART + (((size_t)blockIdx.x*NB + b)*NH + hg + 16)*CKV + c) = acc1;
}

// ---------------- R3: OLAT = sum_p OPART[p] ----------------------------------
__global__ __launch_bounds__(256)
void k_reduce3(float* __restrict__ ws) {
  const int idx = blockIdx.x * 256 + threadIdx.x;
  float4 s = {};
  #pragma unroll 8
  for (int p = 0; p < NPV; ++p) {
    float4 v = *(const float4*)(ws + WS_OPART + (size_t)p*(NB*NH*CKV) + (size_t)idx*4);
    s.x += v.x; s.y += v.y; s.z += v.z; s.w += v.w;
  }
  *(float4*)(ws + WS_OLAT + (size_t)idx*4) = s;
}

// ---------------- K7: UVPART = o_latent @ W_UV (block c-split) --------------
__global__ __launch_bounds__(256)
void k_uv(const float* __restrict__ Wuv, float* __restrict__ ws) {
  __shared__ float4 red_s[4][NB][64];
  const int lane = threadIdx.x & 63, csub = threadIdx.x >> 6;
  const int col4 = blockIdx.x * 64 + lane;
  const int h = col4 >> 5;
  const int k0 = blockIdx.y * 32 + csub * 8;
  const float4* wp = (const float4*)Wuv + (size_t)k0 * 1024 + col4;
  float4 acc[NB] = {};
  #pragma unroll
  for (int i = 0; i < 8; ++i) {
    float4 w4 = wp[(size_t)i * 1024];
    #pragma unroll
    for (int b = 0; b < NB; ++b)
      fma4(acc[b], ws[WS_OLAT + (size_t)(b*NH + h)*CKV + k0 + i], w4);
  }
  #pragma unroll
  for (int b = 0; b < NB; ++b) red_s[csub][b][lane] = acc[b];
  __syncthreads();
  if (csub == 0) {
    #pragma unroll
    for (int b = 0; b < NB; ++b) {
      float4 s = red_s[0][b][lane];
      #pragma unroll
      for (int j = 1; j < 4; ++j) {
        float4 v = red_s[j][b][lane];
        s.x += v.x; s.y += v.y; s.z += v.z; s.w += v.w;
      }
      *(float4*)(ws + WS_UVPART + (size_t)(blockIdx.y*NB + b)*HID + col4*4) = s;
    }
  }
}

// ---------------- R4: ATTN = sum_p UVPART[p] ---------------------------------
__global__ __launch_bounds__(256)
void k_reduce4(float* __restrict__ ws) {
  const int idx = blockIdx.x * 256 + threadIdx.x;
  float4 s = {};
  #pragma unroll
  for (int p = 0; p < NUV; ++p) {
    float4 v = *(const float4*)(ws + WS_UVPART + (size_t)p*(NB*HID) + (size_t)idx*4);
    s.x += v.x; s.y += v.y; s.z += v.z; s.w += v.w;
  }
  *(float4*)(ws + WS_ATTN + (size_t)idx*4) = s;
}

// ---------------- K8: WOPART = attn @ W_O (block k-split) --------------------
__global__ __launch_bounds__(256)
void k_wo(const float* __restrict__ Wo, const float* __restrict__ ws,
          float* __restrict__ wsp) {
  __shared__ float4 red_s[4][NB][64];
  const int lane = threadIdx.x & 63, ksub = threadIdx.x >> 6;
  const int col4 = blockIdx.x * 64 + lane;
  const int k0 = blockIdx.y * 128 + ksub * 32;
  const float4* wp = (const float4*)Wo + (size_t)k0 * 1024 + col4;
  float4 acc[NB] = {};
  #pragma unroll 8
  for (int i = 0; i < 32; ++i) {
    float4 w4 = wp[(size_t)i * 1024];
    #pragma unroll
    for (int b = 0; b < NB; ++b)
      fma4(acc[b], ws[WS_ATTN + b*HID + k0 + i], w4);
  }
  #pragma unroll
  for (int b = 0; b < NB; ++b) red_s[ksub][b][lane] = acc[b];
  __syncthreads();
  if (ksub == 0) {
    #pragma unroll
    for (int b = 0; b < NB; ++b) {
      float4 s = red_s[0][b][lane];
      #pragma unroll
      for (int j = 1; j < 4; ++j) {
        float4 v = red_s[j][b][lane];
        s.x += v.x; s.y += v.y; s.z += v.z; s.w += v.w;
      }
      *(float4*)(wsp + WS_WOPART + (size_t)(blockIdx.y*NB + b)*HID + col4*4) = s;
    }
  }
}

// ---------------- R5: out = sum_p WOPART[p] ----------------------------------
__global__ __launch_bounds__(256)
void k_reduce5(const float* __restrict__ ws, float* __restrict__ out) {
  const int idx = blockIdx.x * 256 + threadIdx.x;
  float4 s = {};
  #pragma unroll 8
  for (int p = 0; p < NWO; ++p) {
    float4 v = *(const float4*)(ws + WS_WOPART + (size_t)p*(NB*HID) + (size_t)idx*4);
    s.x += v.x; s.y += v.y; s.z += v.z; s.w += v.w;
  }
  *(float4*)(out + (size_t)idx*4) = s;
}

// ---------------- K9: cache copy (rows 0..4095) ------------------------------
__global__ __launch_bounds__(256)
void k_copy(const float4* __restrict__ src_ckv,
            const float4* __restrict__ src_kr,
            float4* __restrict__ dst_ckv,
            float4* __restrict__ dst_kr) {
  const int bx = blockIdx.x;
  if (bx < 8192) {
    int b = bx >> 11;
    int idx = (bx & 2047) * 256 + threadIdx.x;
    dst_ckv[(size_t)b*(SK*CKV/4) + idx] = src_ckv[(size_t)b*(SS*CKV/4) + idx];
  } else {
    int bx2 = bx - 8192;
    int b = bx2 >> 8;
    int idx = (bx2 & 255) * 256 + threadIdx.x;
    dst_kr[(size_t)b*(SK*RD/4) + idx] = src_kr[(size_t)b*(SS*RD/4) + idx];
  }
}

extern "C" void kernel_launch(void* const* d_in, const int* in_sizes, int n_in,
                              void* d_out, int out_size, void* d_ws, size_t ws_size,
                              hipStream_t stream) {
  (void)in_sizes; (void)n_in; (void)out_size; (void)ws_size;
  const float* hidden = (const float*)d_in[0];
  const float* mask   = (const float*)d_in[1];
  const float* ckv_c  = (const float*)d_in[2];
  const float* kr_c   = (const float*)d_in[3];
  const float* Wdkv   = (const float*)d_in[4];
  const float* Wuk    = (const float*)d_in[5];
  const float* Wuv    = (const float*)d_in[6];
  const float* Wdq    = (const float*)d_in[7];
  const float* Wuq    = (const float*)d_in[8];
  const float* Wqr    = (const float*)d_in[9];
  const float* Wkr    = (const float*)d_in[10];
  const float* Wo     = (const float*)d_in[11];
  float* out = (float*)d_out;
  float* ws  = (float*)d_ws;
  float* out_ckv = out + NB*HID;
  float* out_kr  = out + NB*HID + (size_t)NB*SK*CKV;

  k_copy<<<9216, 256, 0, stream>>>((const float4*)ckv_c, (const float4*)kr_c,
                                   (float4*)out_ckv, (float4*)out_kr);
  k_proj1<<<dim3(9, NP1), 256, 0, stream>>>(hidden, Wdkv, Wdq, Wkr, ws);
  k_reduce1<<<9, 256, 0, stream>>>(ws, out_ckv, out_kr);
  k_proj2<<<dim3(24, NP2), 256, 0, stream>>>(Wuq, Wqr, ws);
  k_absorb_rope<<<260, 256, 0, stream>>>(Wuk, ws);
  k_scores<<<dim3(129, 2, 4), 256, 0, stream>>>(ckv_c, kr_c, ws);
  k_softmax<<<NB*NH, 256, 0, stream>>>(mask, ws);
  k_pv<<<dim3(NPV, 8, 4), 256, 0, stream>>>(ckv_c, ws);
  k_reduce3<<<64, 256, 0, stream>>>(ws);
  k_uv<<<dim3(16, NUV), 256, 0, stream>>>(Wuv, ws);
  k_reduce4<<<16, 256, 0, stream>>>(ws);
  k_wo<<<dim3(16, NWO), 256, 0, stream>>>(Wo, ws, ws);
  k_reduce5<<<16, 256, 0, stream>>>(ws, out);
}

// Round 9
// 151.242 us; speedup vs baseline: 1.7329x; 1.0304x over previous
//
#include <hip/hip_runtime.h>
#include <math.h>

#define NB 4
#define HID 4096
#define CKV 512
#define CQ 1536
#define NH 32
#define HD 128
#define RD 64
#define SS 4096
#define SK 4097
#define SKP 4100  // padded scores row stride

#define SCALE_F 0.07216878364870322f  // 1/sqrt(192)

#define NP1 64   // proj1 k-partials
#define NP2 24   // proj2 k-partials
#define NPV 32   // pv key-chunks (128 keys)
#define NUV 16   // uv c-partials
#define NWO 32   // wo k-partials

#define SC_D4 36   // scores: 144 dims per c-quarter, in float4
#define SC_STR 148 // scores LDS row stride (floats; 148 mod 32 = 20 -> conflict-free)

// workspace offsets (floats). NO memsets — every cell written before read.
enum : int {
  WS_QABS  = 0,                      // [NB][NH][CKV] pre-scaled
  WS_QROPE = WS_QABS + NB*NH*CKV,    // [NB][NH][RD]  pre-scaled
  WS_KROPE = WS_QROPE + NB*NH*RD,    // [NB][RD]
  WS_CKV   = WS_KROPE + NB*RD,       // [NB][CKV]
  WS_CQ    = WS_CKV + NB*CKV,        // [NB][CQ]
  WS_OLAT  = WS_CQ + NB*CQ,          // [NB][NH][CKV]
  WS_ATTN  = WS_OLAT + NB*NH*CKV,    // [NB][HID]
  WS_SCA   = WS_ATTN + NB*HID,       // [NB][NH][SKP] c-quarter 0 -> probs
  WS_SCB   = WS_SCA + NB*NH*SKP,     // c-quarter 1
  WS_SCC   = WS_SCB + NB*NH*SKP,     // c-quarter 2
  WS_SCD   = WS_SCC + NB*NH*SKP,     // c-quarter 3 (incl rope)
  WS_R1    = WS_SCD + NB*NH*SKP,     // lifetime-shared partials region
  WS_TOTAL = WS_R1 + NPV*NB*NH*CKV
};
#define WS_P1     WS_R1
#define WS_P2     WS_R1
#define WS_OPART  WS_R1
#define WS_UVPART WS_R1
#define WS_WOPART WS_R1

__device__ inline void fma4(float4& a, float s, const float4& v) {
  a.x += s*v.x; a.y += s*v.y; a.z += s*v.z; a.w += s*v.w;
}
__device__ inline float dot4(const float4& a, const float4& b) {
  return a.x*b.x + a.y*b.y + a.z*b.z + a.w*b.w;
}

// ---------------- K1: hidden -> P1 partials (block k-split, LDS reduce) -----
__global__ __launch_bounds__(256)
void k_proj1(const float* __restrict__ hidden,
             const float* __restrict__ Wdkv,
             const float* __restrict__ Wdq,
             const float* __restrict__ Wkr,
             float* __restrict__ ws) {
  __shared__ float4 red_s[4][NB][64];
  const int lane = threadIdx.x & 63, ksub = threadIdx.x >> 6;
  const int col4 = blockIdx.x * 64 + lane;
  const int k0 = blockIdx.y * 64 + ksub * 16;
  const bool valid = col4 < 528;
  float4 acc[NB] = {};
  if (valid) {
    const float* W; int C4, wcol4;
    if (col4 < 128)      { W = Wdkv; C4 = 128; wcol4 = col4; }
    else if (col4 < 512) { W = Wdq;  C4 = 384; wcol4 = col4 - 128; }
    else                 { W = Wkr;  C4 = 16;  wcol4 = col4 - 512; }
    const float4* wp = (const float4*)W + (size_t)k0 * C4 + wcol4;
    #pragma unroll
    for (int i = 0; i < 16; ++i) {
      float4 w4 = wp[(size_t)i * C4];
      #pragma unroll
      for (int b = 0; b < NB; ++b) fma4(acc[b], hidden[b*HID + k0 + i], w4);
    }
  }
  #pragma unroll
  for (int b = 0; b < NB; ++b) red_s[ksub][b][lane] = acc[b];
  __syncthreads();
  if (ksub == 0 && valid) {
    #pragma unroll
    for (int b = 0; b < NB; ++b) {
      float4 s = red_s[0][b][lane];
      #pragma unroll
      for (int j = 1; j < 4; ++j) {
        float4 v = red_s[j][b][lane];
        s.x += v.x; s.y += v.y; s.z += v.z; s.w += v.w;
      }
      *(float4*)(ws + WS_P1 + ((size_t)(blockIdx.y*NB + b)*528 + col4)*4) = s;
    }
  }
}

// ---------------- R1: reduce P1 -> c_KV, c_Q; k_R RoPE; new cache rows ------
__global__ __launch_bounds__(256)
void k_reduce1(float* __restrict__ ws,
               float* __restrict__ out_ckv,
               float* __restrict__ out_kr) {
  const int w = blockIdx.x * 256 + threadIdx.x;  // < 2112
  if (w >= 528*NB) return;
  const int b = w / 528, col4 = w % 528;
  float4 s = {};
  #pragma unroll 8
  for (int p = 0; p < NP1; ++p) {
    float4 v = *(const float4*)(ws + WS_P1 + ((size_t)(p*NB + b)*528 + col4)*4);
    s.x += v.x; s.y += v.y; s.z += v.z; s.w += v.w;
  }
  if (col4 < 128) {
    *(float4*)(ws + WS_CKV + b*CKV + col4*4) = s;
    *(float4*)(out_ckv + (size_t)b*SK*CKV + (size_t)SS*CKV + col4*4) = s;
  } else if (col4 < 512) {
    *(float4*)(ws + WS_CQ + b*CQ + (col4 - 128)*4) = s;
  } else {
    const int c0 = (col4 - 512) * 4;
    const double LN1E4 = 9.210340371976184;
    int i0 = c0 >> 1;
    double a0 = 4096.0 * exp(-(double)i0 / 32.0 * LN1E4);
    double a1 = 4096.0 * exp(-(double)(i0 + 1) / 32.0 * LN1E4);
    float c0f = (float)cos(a0), s0f = (float)sin(a0);
    float c1f = (float)cos(a1), s1f = (float)sin(a1);
    float4 o;
    o.x = s.x*c0f - s.y*s0f;  o.y = s.x*s0f + s.y*c0f;
    o.z = s.z*c1f - s.w*s1f;  o.w = s.z*s1f + s.w*c1f;
    *(float4*)(ws + WS_KROPE + b*RD + c0) = o;
    *(float4*)(out_kr + (size_t)b*SK*RD + (size_t)SS*RD + c0) = o;
  }
}

// ---------------- K2: c_Q -> P2 partials (block k-split, LDS reduce) --------
__global__ __launch_bounds__(256)
void k_proj2(const float* __restrict__ Wuq,
             const float* __restrict__ Wqr,
             float* __restrict__ ws) {
  __shared__ float4 red_s[4][NB][64];
  const int lane = threadIdx.x & 63, ksub = threadIdx.x >> 6;
  const int col4 = blockIdx.x * 64 + lane;   // < 1536
  const int k0 = blockIdx.y * 64 + ksub * 16;
  const float* W; int C4, wcol4;
  if (col4 < 1024) { W = Wuq; C4 = 1024; wcol4 = col4; }
  else             { W = Wqr; C4 = 512;  wcol4 = col4 - 1024; }
  const float4* wp = (const float4*)W + (size_t)k0 * C4 + wcol4;
  const float* act = ws + WS_CQ;
  float4 acc[NB] = {};
  #pragma unroll
  for (int i = 0; i < 16; ++i) {
    float4 w4 = wp[(size_t)i * C4];
    #pragma unroll
    for (int b = 0; b < NB; ++b) fma4(acc[b], act[b*CQ + k0 + i], w4);
  }
  #pragma unroll
  for (int b = 0; b < NB; ++b) red_s[ksub][b][lane] = acc[b];
  __syncthreads();
  if (ksub == 0) {
    #pragma unroll
    for (int b = 0; b < NB; ++b) {
      float4 s = red_s[0][b][lane];
      #pragma unroll
      for (int j = 1; j < 4; ++j) {
        float4 v = red_s[j][b][lane];
        s.x += v.x; s.y += v.y; s.z += v.z; s.w += v.w;
      }
      *(float4*)(ws + WS_P2 + (size_t)(blockIdx.y*NB + b)*6144 + col4*4) = s;
    }
  }
}

// -------- K3: q_abs = q_C @ W_UK^T (×SCALE), P2-reduce fused; q_R RoPE -------
__global__ __launch_bounds__(256)
void k_absorb_rope(const float* __restrict__ Wuk,
                   float* __restrict__ ws) {
  const int bid = blockIdx.x, tid = threadIdx.x;
  if (bid < 256) {
    const int h = bid >> 3, cq = bid & 7;
    __shared__ float qc_s[NB][HD];
    __shared__ float part_s[NB][256];
    for (int e = tid; e < NB*HD; e += 256) {
      int b = e >> 7, d = e & 127;
      float v = 0.f;
      #pragma unroll
      for (int p = 0; p < NP2; ++p)
        v += ws[WS_P2 + (size_t)(p*NB + b)*6144 + h*HD + d];
      qc_s[b][d] = v;
    }
    __syncthreads();
    const int c = cq*64 + (tid & 63);
    const int dg = tid >> 6;
    const float4* wrow = (const float4*)(Wuk + (size_t)c*(NH*HD) + h*HD + dg*32);
    float acc[NB] = {0,0,0,0};
    #pragma unroll
    for (int d4 = 0; d4 < 8; ++d4) {
      float4 w4 = wrow[d4];
      #pragma unroll
      for (int b = 0; b < NB; ++b)
        acc[b] += dot4(w4, *(const float4*)&qc_s[b][dg*32 + d4*4]);
    }
    #pragma unroll
    for (int b = 0; b < NB; ++b) part_s[b][tid] = acc[b];
    __syncthreads();
    if (tid < 64) {
      #pragma unroll
      for (int b = 0; b < NB; ++b) {
        float v = part_s[b][tid] + part_s[b][tid+64] + part_s[b][tid+128] + part_s[b][tid+192];
        ws[WS_QABS + (size_t)(b*NH + h)*CKV + cq*64 + tid] = v * SCALE_F;
      }
    }
  } else {
    const int b = bid - 256;
    const double LN1E4 = 9.210340371976184;
    for (int pid = tid; pid < NH*32; pid += 256) {
      int h = pid >> 5, i = pid & 31;
      float x1 = 0.f, x2 = 0.f;
      #pragma unroll
      for (int p = 0; p < NP2; ++p) {
        const float* base = ws + WS_P2 + (size_t)(p*NB + b)*6144 + 4096 + h*RD + 2*i;
        x1 += base[0]; x2 += base[1];
      }
      double ang = 4096.0 * exp(-(double)i / 32.0 * LN1E4);
      float cs = (float)cos(ang), sn = (float)sin(ang);
      ws[WS_QROPE + (b*NH + h)*RD + 2*i]     = (x1*cs - x2*sn) * SCALE_F;
      ws[WS_QROPE + (b*NH + h)*RD + 2*i + 1] = (x1*sn + x2*cs) * SCALE_F;
    }
  }
}

// ---------------- K4: scores v4 — in-lane dot, dual LDS tiles, NO shfl ------
// block: 32 heads × 32 keys × 144-dim c-quarter. Thread = (h=tid>>3, 4 keys
// strided by 8). grid (129, 4, 4) = 2064 blocks, 37 KB LDS -> 4 blocks/CU.
// c-quarter 3 spans latent[432,512)+rope[0,64) — gathered at staging.
__global__ __launch_bounds__(256)
void k_scores(const float* __restrict__ kv_cache,
              const float* __restrict__ kr_cache,
              float* __restrict__ ws) {
  __shared__ float kv_s[32*SC_STR];
  __shared__ float q_s[32*SC_STR];
  const int tid = threadIdx.x;
  const int b  = blockIdx.z;
  const int cs = blockIdx.y;
  const int k0 = blockIdx.x * 32;
  const int r = tid >> 3, t7 = tid & 7;
  // ---- stage kv row r (guarded source select incl. tail key SS and rope)
  {
    const int k = k0 + r;
    const float4* kvr = (const float4*)(ws + WS_CKV);    // dummy default
    const float4* krr = (const float4*)(ws + WS_KROPE);
    const bool valid = (k <= SS);
    if (k < SS)       { kvr = (const float4*)(kv_cache + ((size_t)b*SS + k)*CKV);
                        krr = (const float4*)(kr_cache + ((size_t)b*SS + k)*RD); }
    else if (k == SS) { kvr = (const float4*)(ws + WS_CKV + b*CKV);
                        krr = (const float4*)(ws + WS_KROPE + b*RD); }
    #pragma unroll
    for (int i = 0; i < 5; ++i) {
      int c4 = t7 + 8*i;
      if (c4 < SC_D4) {
        int g4 = cs*SC_D4 + c4;
        float4 v = make_float4(0.f, 0.f, 0.f, 0.f);
        if (valid) v = (g4 < 128) ? kvr[g4] : krr[g4 - 128];
        *(float4*)&kv_s[r*SC_STR + c4*4] = v;
      }
    }
    // ---- stage q row r (q_abs / q_rope, both pre-scaled)
    const float4* qa = (const float4*)(ws + WS_QABS + (size_t)(b*NH + r)*CKV);
    const float4* qr = (const float4*)(ws + WS_QROPE + (size_t)(b*NH + r)*RD);
    #pragma unroll
    for (int i = 0; i < 5; ++i) {
      int c4 = t7 + 8*i;
      if (c4 < SC_D4) {
        int g4 = cs*SC_D4 + c4;
        float4 v = (g4 < 128) ? qa[g4] : qr[g4 - 128];
        *(float4*)&q_s[r*SC_STR + c4*4] = v;
      }
    }
  }
  __syncthreads();
  // ---- in-lane dot: thread = (h=r, keys t7+8j); conflict-free strides
  float acc[4] = {0.f, 0.f, 0.f, 0.f};
  const float* qrow = &q_s[r*SC_STR];
  #pragma unroll 4
  for (int c4 = 0; c4 < SC_D4; ++c4) {
    float4 q4 = *(const float4*)(qrow + c4*4);
    #pragma unroll
    for (int j = 0; j < 4; ++j) {
      float4 kv4 = *(const float4*)&kv_s[(t7 + 8*j)*SC_STR + c4*4];
      acc[j] += dot4(q4, kv4);
    }
  }
  float* sbuf = ws + (cs == 0 ? WS_SCA : cs == 1 ? WS_SCB : cs == 2 ? WS_SCC : WS_SCD);
  float* srow = sbuf + (size_t)(b*NH + r)*SKP;
  #pragma unroll
  for (int j = 0; j < 4; ++j) {
    int k = k0 + t7 + 8*j;
    if (k < SK) srow[k] = acc[j];
  }
}

// ---------------- K5: softmax(SCA+SCB+SCC+SCD+mask) -> probs in SCA ---------
__global__ __launch_bounds__(256)
void k_softmax(const float* __restrict__ mask, float* __restrict__ ws) {
  __shared__ float red[256];
  const int tid = threadIdx.x;
  const int b = blockIdx.x >> 5;
  float* sa = ws + WS_SCA + (size_t)blockIdx.x * SKP;
  const float* sb = ws + WS_SCB + (size_t)blockIdx.x * SKP;
  const float* sc = ws + WS_SCC + (size_t)blockIdx.x * SKP;
  const float* sd = ws + WS_SCD + (size_t)blockIdx.x * SKP;
  const float* mrow = mask + (size_t)b * SK;
  float v[17];
  float m = -INFINITY;
  #pragma unroll
  for (int r = 0; r < 17; ++r) {
    int k = tid + r*256;
    v[r] = (k < SK) ? (sa[k] + sb[k] + sc[k] + sd[k] + mrow[k] * (-1e9f)) : -INFINITY;
    m = fmaxf(m, v[r]);
  }
  red[tid] = m; __syncthreads();
  for (int st = 128; st > 0; st >>= 1) {
    if (tid < st) red[tid] = fmaxf(red[tid], red[tid+st]);
    __syncthreads();
  }
  m = red[0]; __syncthreads();
  float e[17];
  float l = 0.f;
  #pragma unroll
  for (int r = 0; r < 17; ++r) {
    int k = tid + r*256;
    e[r] = (k < SK) ? __expf(v[r] - m) : 0.f;
    l += e[r];
  }
  red[tid] = l; __syncthreads();
  for (int st = 128; st > 0; st >>= 1) {
    if (tid < st) red[tid] += red[tid+st];
    __syncthreads();
  }
  float inv = 1.f / red[0];
  #pragma unroll
  for (int r = 0; r < 17; ++r) {
    int k = tid + r*256;
    if (k < SK) sa[k] = e[r] * inv;
  }
}

// ---------------- K6: o_latent partials — LDS-staged probs ------------------
__global__ __launch_bounds__(256)
void k_pv(const float* __restrict__ kv_cache, float* __restrict__ ws) {
  __shared__ float p_s[32][132];
  const int tid = threadIdx.x;
  const int c4 = tid & 15, hg = tid >> 4;
  const int b  = blockIdx.z;
  const int c  = blockIdx.y * 64 + c4 * 4;
  const int k0 = blockIdx.x * 128;
  #pragma unroll
  for (int j = 0; j < 4; ++j) {
    int e = tid + j*256;
    int h = e >> 5, k4 = e & 31;
    *(float4*)&p_s[h][k4*4] =
        *(const float4*)(ws + WS_SCA + (size_t)(b*NH + h)*SKP + k0 + k4*4);
  }
  __syncthreads();
  const float* kvp = kv_cache + ((size_t)b*SS + k0)*CKV + c;
  float4 acc0 = {}, acc1 = {};
  #pragma unroll 4
  for (int kk = 0; kk < 128; kk += 4) {
    float4 kv4[4];
    #pragma unroll
    for (int j = 0; j < 4; ++j)
      kv4[j] = *(const float4*)(kvp + (size_t)(kk + j)*CKV);
    float4 p4a = *(const float4*)&p_s[hg][kk];
    float4 p4b = *(const float4*)&p_s[hg + 16][kk];
    fma4(acc0, p4a.x, kv4[0]); fma4(acc1, p4b.x, kv4[0]);
    fma4(acc0, p4a.y, kv4[1]); fma4(acc1, p4b.y, kv4[1]);
    fma4(acc0, p4a.z, kv4[2]); fma4(acc1, p4b.z, kv4[2]);
    fma4(acc0, p4a.w, kv4[3]); fma4(acc1, p4b.w, kv4[3]);
  }
  if (blockIdx.x == NPV - 1) {
    float4 kv = *(const float4*)(ws + WS_CKV + b*CKV + c);
    float pa = ws[WS_SCA + (size_t)(b*NH + hg)*SKP + SS];
    float pb = ws[WS_SCA + (size_t)(b*NH + hg + 16)*SKP + SS];
    fma4(acc0, pa, kv);
    fma4(acc1, pb, kv);
  }
  *(float4*)(ws + WS_OPART + (((size_t)blockIdx.x*NB + b)*NH + hg)*CKV + c) = acc0;
  *(float4*)(ws + WS_OPART + (((size_t)blockIdx.x*NB + b)*NH + hg + 16)*CKV + c) = acc1;
}

// ---------------- R3: OLAT = sum_p OPART[p] ----------------------------------
__global__ __launch_bounds__(256)
void k_reduce3(float* __restrict__ ws) {
  const int idx = blockIdx.x * 256 + threadIdx.x;
  float4 s = {};
  #pragma unroll 8
  for (int p = 0; p < NPV; ++p) {
    float4 v = *(const float4*)(ws + WS_OPART + (size_t)p*(NB*NH*CKV) + (size_t)idx*4);
    s.x += v.x; s.y += v.y; s.z += v.z; s.w += v.w;
  }
  *(float4*)(ws + WS_OLAT + (size_t)idx*4) = s;
}

// ---------------- K7: UVPART = o_latent @ W_UV (block c-split) --------------
__global__ __launch_bounds__(256)
void k_uv(const float* __restrict__ Wuv, float* __restrict__ ws) {
  __shared__ float4 red_s[4][NB][64];
  const int lane = threadIdx.x & 63, csub = threadIdx.x >> 6;
  const int col4 = blockIdx.x * 64 + lane;
  const int h = col4 >> 5;
  const int k0 = blockIdx.y * 32 + csub * 8;
  const float4* wp = (const float4*)Wuv + (size_t)k0 * 1024 + col4;
  float4 acc[NB] = {};
  #pragma unroll
  for (int i = 0; i < 8; ++i) {
    float4 w4 = wp[(size_t)i * 1024];
    #pragma unroll
    for (int b = 0; b < NB; ++b)
      fma4(acc[b], ws[WS_OLAT + (size_t)(b*NH + h)*CKV + k0 + i], w4);
  }
  #pragma unroll
  for (int b = 0; b < NB; ++b) red_s[csub][b][lane] = acc[b];
  __syncthreads();
  if (csub == 0) {
    #pragma unroll
    for (int b = 0; b < NB; ++b) {
      float4 s = red_s[0][b][lane];
      #pragma unroll
      for (int j = 1; j < 4; ++j) {
        float4 v = red_s[j][b][lane];
        s.x += v.x; s.y += v.y; s.z += v.z; s.w += v.w;
      }
      *(float4*)(ws + WS_UVPART + (size_t)(blockIdx.y*NB + b)*HID + col4*4) = s;
    }
  }
}

// ---------------- R4: ATTN = sum_p UVPART[p] ---------------------------------
__global__ __launch_bounds__(256)
void k_reduce4(float* __restrict__ ws) {
  const int idx = blockIdx.x * 256 + threadIdx.x;
  float4 s = {};
  #pragma unroll
  for (int p = 0; p < NUV; ++p) {
    float4 v = *(const float4*)(ws + WS_UVPART + (size_t)p*(NB*HID) + (size_t)idx*4);
    s.x += v.x; s.y += v.y; s.z += v.z; s.w += v.w;
  }
  *(float4*)(ws + WS_ATTN + (size_t)idx*4) = s;
}

// ---------------- K8: WOPART = attn @ W_O (block k-split) --------------------
__global__ __launch_bounds__(256)
void k_wo(const float* __restrict__ Wo, const float* __restrict__ ws,
          float* __restrict__ wsp) {
  __shared__ float4 red_s[4][NB][64];
  const int lane = threadIdx.x & 63, ksub = threadIdx.x >> 6;
  const int col4 = blockIdx.x * 64 + lane;
  const int k0 = blockIdx.y * 128 + ksub * 32;
  const float4* wp = (const float4*)Wo + (size_t)k0 * 1024 + col4;
  float4 acc[NB] = {};
  #pragma unroll 8
  for (int i = 0; i < 32; ++i) {
    float4 w4 = wp[(size_t)i * 1024];
    #pragma unroll
    for (int b = 0; b < NB; ++b)
      fma4(acc[b], ws[WS_ATTN + b*HID + k0 + i], w4);
  }
  #pragma unroll
  for (int b = 0; b < NB; ++b) red_s[ksub][b][lane] = acc[b];
  __syncthreads();
  if (ksub == 0) {
    #pragma unroll
    for (int b = 0; b < NB; ++b) {
      float4 s = red_s[0][b][lane];
      #pragma unroll
      for (int j = 1; j < 4; ++j) {
        float4 v = red_s[j][b][lane];
        s.x += v.x; s.y += v.y; s.z += v.z; s.w += v.w;
      }
      *(float4*)(wsp + WS_WOPART + (size_t)(blockIdx.y*NB + b)*HID + col4*4) = s;
    }
  }
}

// ---------------- R5: out = sum_p WOPART[p] ----------------------------------
__global__ __launch_bounds__(256)
void k_reduce5(const float* __restrict__ ws, float* __restrict__ out) {
  const int idx = blockIdx.x * 256 + threadIdx.x;
  float4 s = {};
  #pragma unroll 8
  for (int p = 0; p < NWO; ++p) {
    float4 v = *(const float4*)(ws + WS_WOPART + (size_t)p*(NB*HID) + (size_t)idx*4);
    s.x += v.x; s.y += v.y; s.z += v.z; s.w += v.w;
  }
  *(float4*)(out + (size_t)idx*4) = s;
}

// ---------------- K9: cache copy (rows 0..4095) ------------------------------
__global__ __launch_bounds__(256)
void k_copy(const float4* __restrict__ src_ckv,
            const float4* __restrict__ src_kr,
            float4* __restrict__ dst_ckv,
            float4* __restrict__ dst_kr) {
  const int bx = blockIdx.x;
  if (bx < 8192) {
    int b = bx >> 11;
    int idx = (bx & 2047) * 256 + threadIdx.x;
    dst_ckv[(size_t)b*(SK*CKV/4) + idx] = src_ckv[(size_t)b*(SS*CKV/4) + idx];
  } else {
    int bx2 = bx - 8192;
    int b = bx2 >> 8;
    int idx = (bx2 & 255) * 256 + threadIdx.x;
    dst_kr[(size_t)b*(SK*RD/4) + idx] = src_kr[(size_t)b*(SS*RD/4) + idx];
  }
}

extern "C" void kernel_launch(void* const* d_in, const int* in_sizes, int n_in,
                              void* d_out, int out_size, void* d_ws, size_t ws_size,
                              hipStream_t stream) {
  (void)in_sizes; (void)n_in; (void)out_size; (void)ws_size;
  const float* hidden = (const float*)d_in[0];
  const float* mask   = (const float*)d_in[1];
  const float* ckv_c  = (const float*)d_in[2];
  const float* kr_c   = (const float*)d_in[3];
  const float* Wdkv   = (const float*)d_in[4];
  const float* Wuk    = (const float*)d_in[5];
  const float* Wuv    = (const float*)d_in[6];
  const float* Wdq    = (const float*)d_in[7];
  const float* Wuq    = (const float*)d_in[8];
  const float* Wqr    = (const float*)d_in[9];
  const float* Wkr    = (const float*)d_in[10];
  const float* Wo     = (const float*)d_in[11];
  float* out = (float*)d_out;
  float* ws  = (float*)d_ws;
  float* out_ckv = out + NB*HID;
  float* out_kr  = out + NB*HID + (size_t)NB*SK*CKV;

  k_copy<<<9216, 256, 0, stream>>>((const float4*)ckv_c, (const float4*)kr_c,
                                   (float4*)out_ckv, (float4*)out_kr);
  k_proj1<<<dim3(9, NP1), 256, 0, stream>>>(hidden, Wdkv, Wdq, Wkr, ws);
  k_reduce1<<<9, 256, 0, stream>>>(ws, out_ckv, out_kr);
  k_proj2<<<dim3(24, NP2), 256, 0, stream>>>(Wuq, Wqr, ws);
  k_absorb_rope<<<260, 256, 0, stream>>>(Wuk, ws);
  k_scores<<<dim3(129, 4, 4), 256, 0, stream>>>(ckv_c, kr_c, ws);
  k_softmax<<<NB*NH, 256, 0, stream>>>(mask, ws);
  k_pv<<<dim3(NPV, 8, 4), 256, 0, stream>>>(ckv_c, ws);
  k_reduce3<<<64, 256, 0, stream>>>(ws);
  k_uv<<<dim3(16, NUV), 256, 0, stream>>>(Wuv, ws);
  k_reduce4<<<16, 256, 0, stream>>>(ws);
  k_wo<<<dim3(16, NWO), 256, 0, stream>>>(Wo, ws, ws);
  k_reduce5<<<16, 256, 0, stream>>>(ws, out);
}